// Round 1
// baseline (449.116 us; speedup 1.0000x reference)
//
#include <hip/hip_runtime.h>
#include <stdint.h>

#define ALPHA 0.2f
#define EPSV  1e-5f

typedef unsigned short u16;
typedef unsigned int   u32;
typedef unsigned long long u64;
typedef __bf16 bf16x8 __attribute__((ext_vector_type(8)));
typedef __bf16 bf16x2 __attribute__((ext_vector_type(2)));
typedef float  f32x4  __attribute__((ext_vector_type(4)));

#define NB 8
#define NS 64
#define NN 256
#define NF 16
#define NH 16
#define NC 4096     // N*H
#define NK 12288    // NC*3
#define NP 512      // B*S (GEMM M / column count)
#define SROW 66     // padded rows per batch in Sp (1 zero + 64 + 1 zero)

__device__ __forceinline__ u16 f2b(float f){
  u32 u = __float_as_uint(f);
  u32 r = u + 0x7fffu + ((u>>16)&1u);   // round-nearest-even
  return (u16)(r>>16);
}
__device__ __forceinline__ u32 pack2(float a, float b){ return (u32)f2b(a) | ((u32)f2b(b)<<16); }
__device__ __forceinline__ void un2(u32 v, float& lo, float& hi){
  lo = __uint_as_float(v<<16); hi = __uint_as_float(v & 0xffff0000u);
}
__device__ __forceinline__ void gld16(void* lds, const void* g){
  __builtin_amdgcn_global_load_lds((const __attribute__((address_space(1))) u32*)g,
                                   (__attribute__((address_space(3))) u32*)lds, 16, 0, 0);
}
// 8 fp32 -> 8 bf16 (16B)
__device__ __forceinline__ uint4 cvt8(f32x4 a, f32x4 b){
  union { uint4 u; bf16x2 h[4]; } r;
  r.h[0] = (bf16x2){(__bf16)a[0], (__bf16)a[1]};
  r.h[1] = (bf16x2){(__bf16)a[2], (__bf16)a[3]};
  r.h[2] = (bf16x2){(__bf16)b[0], (__bf16)b[1]};
  r.h[3] = (bf16x2){(__bf16)b[2], (__bf16)b[3]};
  return r.u;
}

// ------- k_adj: adjacency -> bitmask, + zero Sp pad rows (64 blocks) ------
__global__ __launch_bounds__(256) void k_adj(const float* __restrict__ adj,
                                             u64* __restrict__ am,
                                             uint4* __restrict__ spz){
  int w = threadIdx.x>>6, l = threadIdx.x&63;
  int row = blockIdx.x*4 + w;
  #pragma unroll
  for(int g=0;g<4;g++){
    float v = adj[(size_t)row*NN + g*64 + l];
    u64 m = __ballot(v > 0.f);
    if(l==0) am[row*4+g] = m;
  }
  if(spz){
    // zero the 16 pad rows of Sp: rows b*66+0 and b*66+65, 8192 B each
    int g = blockIdx.x*256 + threadIdx.x;    // 0..16383
    if(g < 8192){
      int r = g>>9;                          // pad row id 0..15
      int b = r>>1;
      size_t prow = (size_t)b*SROW + ((r&1) ? (SROW-1) : 0);
      spz[prow*512 + (g&511)] = (uint4){0,0,0,0};
    }
  }
}

// ------- k_cw: conv_w [co][ci][3] fp32 -> Bw [co][k*4096+ci] bf16 --------
__global__ __launch_bounds__(256) void k_cw(const float* __restrict__ cw,
                                            u16* __restrict__ Bw){
  __shared__ __align__(16) float rs_[NK];
  int t = threadIdx.x, co = blockIdx.x;
  const float* src = cw + (size_t)co*NK;
  #pragma unroll
  for(int i=0;i<12;i++)
    gld16(rs_ + (i*256 + t)*4, src + (i*256 + t)*4);
  __syncthreads();
  u16* dst = Bw + (size_t)co*NK;
  #pragma unroll
  for(int c=0;c<6;c++){
    int o  = c*2048 + t*8;        // output K index (k-major)
    int k  = o>>12, ci = o & 4095;
    const float* p = rs_ + ci*3 + k;
    union { uint4 u; u16 h[8]; } r;
    #pragma unroll
    for(int j=0;j<8;j++) r.h[j] = f2b(p[j*3]);
    *(uint4*)(dst + o) = r.u;
  }
}

// --- k_attn: per block bs, Wh + masked softmax + spatial -> Sp row (bf16)
// Sp[b][s+1][ci] = spatial[b][s][ci]; rows 0 and 65 per batch are zero pads.
__global__ __launch_bounds__(256) void k_attn(
    const float* __restrict__ x, const float* __restrict__ W,
    const float* __restrict__ a1, const float* __restrict__ a2,
    const u64* __restrict__ am, u16* __restrict__ Sp){
  __shared__ __align__(16) float Ws[NF][NH];
  __shared__ float a1s[NH], a2s[NH];
  __shared__ __align__(16) float Whs[NN][NH];
  __shared__ float f2s[NN];
  int t = threadIdx.x, bs = blockIdx.x;
  int b = bs>>6, s = bs&63;
  Ws[t>>4][t&15] = W[t];
  if(t<NH){ a1s[t]=a1[t]; a2s[t]=a2[t]; }
  u64 mg[4];
  #pragma unroll
  for(int g=0;g<4;g++) mg[g] = am[t*4+g];
  __syncthreads();

  const float* xp = x + ((size_t)bs*NN + t)*NF;
  float xr[16];
  #pragma unroll
  for(int g=0;g<4;g++) *(f32x4*)&xr[g*4] = ((const f32x4*)xp)[g];
  float wh[16];
  #pragma unroll
  for(int h=0;h<16;h++) wh[h]=0.f;
  #pragma unroll
  for(int f=0;f<16;f++){
    float xf = xr[f];
    #pragma unroll
    for(int h=0;h<16;h++) wh[h] = fmaf(xf, Ws[f][h], wh[h]);
  }
  float fi=0.f, s2=0.f;
  #pragma unroll
  for(int h=0;h<16;h++){ fi=fmaf(wh[h],a1s[h],fi); s2=fmaf(wh[h],a2s[h],s2); }
  #pragma unroll
  for(int g=0;g<4;g++) ((f32x4*)Whs[t])[g] = *(f32x4*)&wh[g*4];
  f2s[t] = s2;
  __syncthreads();

  // single-pass masked softmax (no max-subtract: |e| small in fp32)
  float den = 0.f;
  f32x4 a0={0,0,0,0}, a1v={0,0,0,0}, a2v={0,0,0,0}, a3v={0,0,0,0};
  #pragma unroll
  for(int g=0;g<4;g++){
    u64 mm = mg[g];
    for(int jj=0;jj<64;jj++){
      int j = g*64+jj;
      float e = fi + f2s[j];
      e = e > 0.f ? e : ALPHA*e;
      float p = ((mm>>jj)&1ull) ? __expf(e) : 0.f;
      den += p;
      const f32x4* wr = (const f32x4*)Whs[j];
      a0 += wr[0]*p; a1v += wr[1]*p; a2v += wr[2]*p; a3v += wr[3]*p;
    }
  }
  float inv = 1.f/fmaxf(den, 1e-30f);
  f32x4 o0 = a0*inv, o1 = a1v*inv, o2 = a2v*inv, o3 = a3v*inv;

  // coalesced bf16 row store: thread t covers ci = t*16 .. t*16+15 (32 B)
  uint4 w0 = cvt8(o0,o1), w1 = cvt8(o2,o3);
  uint4* op = (uint4*)(Sp + ((size_t)(b*SROW + s + 1))*NC) + t*2;
  op[0] = w0; op[1] = w1;
}

// ------- k_gemm: yp[col][co] = sum_K A[col][K] * Bw[co][K] ---------------
// A row (col = b*64+s) is the contiguous 12288-elem window starting at
// Sp[b][s][0] (tap-major im2col for free). Both operands bf16 via
// global_load_lds (m97 structure). Split-K over blockIdx.y.
__global__ __launch_bounds__(256) void k_gemm(
    const u16* __restrict__ Asp, const u16* __restrict__ Bw,
    u16* __restrict__ yp, int kchunk){
  __shared__ __align__(16) u16 As0[128*32];
  __shared__ __align__(16) u16 As1[128*32];
  __shared__ __align__(16) u16 Bs0[128*32];
  __shared__ __align__(16) u16 Bs1[128*32];
  int t = threadIdx.x;
  int id = blockIdx.x;               // 0..127
  int xr_ = id & 7, q0 = id >> 3;    // xcd residue, remainder
  int mI = q0 & 3, nhi = q0 >> 2;    // m in [0,4), nhi in [0,4)
  int m0 = mI*128, n0 = (nhi*8 + xr_)*128;
  int kbeg = blockIdx.y*kchunk;
  f32x4 acc[4][4];
  #pragma unroll
  for(int i=0;i<4;i++)
    #pragma unroll
    for(int j=0;j<4;j++) acc[i][j] = (f32x4){0,0,0,0};

  int l = t&63, w = t>>6;
  int wm = (w&1)*64, wn = (w>>1)*64;
  int q = l>>4, r16 = l&15;

  int c0 = t, c1 = t+256;
  // chunk c: tile row = c>>2, K-word = c&3 (8 K-elements each).
  int mA0 = m0 + (c0>>2), mA1 = m0 + (c1>>2);
  const u16* ga0 = Asp + (size_t)((mA0>>6)*SROW + (mA0&63))*NC + (c0&3)*8;
  const u16* ga1 = Asp + (size_t)((mA1>>6)*SROW + (mA1&63))*NC + (c1&3)*8;
  const u16* gb0 = Bw  + (size_t)(n0 + (c0>>2))*NK + (c0&3)*8;
  const u16* gb1 = Bw  + (size_t)(n0 + (c1>>2))*NK + (c1&3)*8;
  u16 *la00 = As0 + c0*8, *la01 = As0 + c1*8;
  u16 *la10 = As1 + c0*8, *la11 = As1 + c1*8;
  u16 *lb00 = Bs0 + c0*8, *lb01 = Bs0 + c1*8;
  u16 *lb10 = Bs1 + c0*8, *lb11 = Bs1 + c1*8;

  for(int kk=0; kk<kchunk; kk+=64){
    int k0 = kbeg + kk;
    __syncthreads();                       // prior iter's LDS reads done
    gld16(la00, ga0 + k0);      gld16(la01, ga1 + k0);
    gld16(la10, ga0 + k0 + 32); gld16(la11, ga1 + k0 + 32);
    gld16(lb00, gb0 + k0);      gld16(lb01, gb1 + k0);
    gld16(lb10, gb0 + k0 + 32); gld16(lb11, gb1 + k0 + 32);
    __syncthreads();                       // staging visible (vmcnt drain)
    {
      bf16x8 af[4], bfr[4];
      #pragma unroll
      for(int mt=0;mt<4;mt++) af[mt]  = *(const bf16x8*)(As0 + (wm+mt*16+r16)*32 + q*8);
      #pragma unroll
      for(int nt=0;nt<4;nt++) bfr[nt] = *(const bf16x8*)(Bs0 + (wn+nt*16+r16)*32 + q*8);
      #pragma unroll
      for(int mt=0;mt<4;mt++)
        #pragma unroll
        for(int nt=0;nt<4;nt++)
          acc[mt][nt] = __builtin_amdgcn_mfma_f32_16x16x32_bf16(af[mt], bfr[nt], acc[mt][nt], 0,0,0);
    }
    {
      bf16x8 af[4], bfr[4];
      #pragma unroll
      for(int mt=0;mt<4;mt++) af[mt]  = *(const bf16x8*)(As1 + (wm+mt*16+r16)*32 + q*8);
      #pragma unroll
      for(int nt=0;nt<4;nt++) bfr[nt] = *(const bf16x8*)(Bs1 + (wn+nt*16+r16)*32 + q*8);
      #pragma unroll
      for(int mt=0;mt<4;mt++)
        #pragma unroll
        for(int nt=0;nt<4;nt++)
          acc[mt][nt] = __builtin_amdgcn_mfma_f32_16x16x32_bf16(af[mt], bfr[nt], acc[mt][nt], 0,0,0);
    }
  }
  u16* op = yp + (size_t)blockIdx.y*NP*NC;
  #pragma unroll
  for(int mt=0;mt<4;mt++)
    #pragma unroll
    for(int nt=0;nt<4;nt++)
      #pragma unroll
      for(int rr=0;rr<4;rr++){
        int m = m0 + wm + mt*16 + q*4 + rr;   // C/D: row = quad*4+reg
        int n = n0 + wn + nt*16 + r16;        //      col = lane&15
        op[(size_t)m*NC + n] = f2b(acc[mt][nt][rr]);
      }
}

// ====================== fallback (old) path kernels ======================
// Used only if workspace can't hold the 100 MB transposed weights.
__global__ __launch_bounds__(256) void k_attn_s(
    const float* __restrict__ x, const float* __restrict__ W,
    const float* __restrict__ a1, const float* __restrict__ a2,
    const u64* __restrict__ am, u16* __restrict__ Bt){
  __shared__ __align__(16) float Ws[NF][NH];
  __shared__ float a1s[NH], a2s[NH];
  __shared__ __align__(16) float Whs[NN][NH];
  __shared__ float f2s[NN];
  int t = threadIdx.x, bs = blockIdx.x;
  int b = bs>>6, s = bs&63;
  Ws[t>>4][t&15] = W[t];
  if(t<NH){ a1s[t]=a1[t]; a2s[t]=a2[t]; }
  u64 mg[4];
  #pragma unroll
  for(int g=0;g<4;g++) mg[g] = am[t*4+g];
  __syncthreads();

  const float* xp = x + ((size_t)bs*NN + t)*NF;
  float xr[16];
  #pragma unroll
  for(int g=0;g<4;g++) *(f32x4*)&xr[g*4] = ((const f32x4*)xp)[g];
  float wh[16];
  #pragma unroll
  for(int h=0;h<16;h++) wh[h]=0.f;
  #pragma unroll
  for(int f=0;f<16;f++){
    float xf = xr[f];
    #pragma unroll
    for(int h=0;h<16;h++) wh[h] = fmaf(xf, Ws[f][h], wh[h]);
  }
  float fi=0.f, s2=0.f;
  #pragma unroll
  for(int h=0;h<16;h++){ fi=fmaf(wh[h],a1s[h],fi); s2=fmaf(wh[h],a2s[h],s2); }
  #pragma unroll
  for(int g=0;g<4;g++) ((f32x4*)Whs[t])[g] = *(f32x4*)&wh[g*4];
  f2s[t] = s2;
  __syncthreads();

  float den = 0.f;
  f32x4 a0={0,0,0,0}, a1v={0,0,0,0}, a2v={0,0,0,0}, a3v={0,0,0,0};
  #pragma unroll
  for(int g=0;g<4;g++){
    u64 mm = mg[g];
    for(int jj=0;jj<64;jj++){
      int j = g*64+jj;
      float e = fi + f2s[j];
      e = e > 0.f ? e : ALPHA*e;
      float p = ((mm>>jj)&1ull) ? __expf(e) : 0.f;
      den += p;
      const f32x4* wr = (const f32x4*)Whs[j];
      a0 += wr[0]*p; a1v += wr[1]*p; a2v += wr[2]*p; a3v += wr[3]*p;
    }
  }
  float inv = 1.f/fmaxf(den, 1e-30f);
  float vals[16];
  *(f32x4*)&vals[0]  = a0*inv;  *(f32x4*)&vals[4]  = a1v*inv;
  *(f32x4*)&vals[8]  = a2v*inv; *(f32x4*)&vals[12] = a3v*inv;

  #pragma unroll
  for(int k=0;k<3;k++){
    int cs = s + 1 - k;
    if(cs >= 0 && cs < NS){
      size_t base = ((size_t)(b*NS+cs))*NK + (size_t)t*48 + k;
      #pragma unroll
      for(int h=0;h<16;h++) Bt[base + h*3] = f2b(vals[h]);
    }
  }
  if(s == 0){
    size_t base = ((size_t)(b*NS))*NK + (size_t)t*48;
    #pragma unroll
    for(int h=0;h<16;h++) Bt[base + h*3] = 0;
  }
  if(s == NS-1){
    size_t base = ((size_t)(b*NS+NS-1))*NK + (size_t)t*48 + 2;
    #pragma unroll
    for(int h=0;h<16;h++) Bt[base + h*3] = 0;
  }
}

__global__ __launch_bounds__(256) void k_gemm_f(
    const u16* __restrict__ Abt, const float* __restrict__ Bwf,
    u16* __restrict__ yp, int kchunk){
  __shared__ __align__(16) u16 As0[128*32];
  __shared__ __align__(16) u16 As1[128*32];
  __shared__ __align__(16) u16 Bs0[128*32];
  __shared__ __align__(16) u16 Bs1[128*32];
  int t = threadIdx.x;
  int id = blockIdx.x;
  int xr_ = id & 7, q0 = id >> 3;
  int mI = q0 & 3, nhi = q0 >> 2;
  int m0 = mI*128, n0 = (nhi*8 + xr_)*128;
  int kbeg = blockIdx.y*kchunk;
  f32x4 acc[4][4];
  #pragma unroll
  for(int i=0;i<4;i++)
    #pragma unroll
    for(int j=0;j<4;j++) acc[i][j] = (f32x4){0,0,0,0};

  int l = t&63, w = t>>6;
  int wm = (w&1)*64, wn = (w>>1)*64;
  int q = l>>4, r16 = l&15;

  int c0 = t, c1 = t+256;
  const u16*   ga0 = Abt + (size_t)(m0 + (c0>>2))*NK + (c0&3)*8;
  const u16*   ga1 = Abt + (size_t)(m0 + (c1>>2))*NK + (c1&3)*8;
  const float* gb0 = Bwf + (size_t)(n0 + (c0>>2))*NK + (c0&3)*8;
  const float* gb1 = Bwf + (size_t)(n0 + (c1>>2))*NK + (c1&3)*8;
  u16 *la00 = As0 + c0*8, *la01 = As0 + c1*8;
  u16 *la10 = As1 + c0*8, *la11 = As1 + c1*8;
  u16 *lb00 = Bs0 + c0*8, *lb01 = Bs0 + c1*8;
  u16 *lb10 = Bs1 + c0*8, *lb11 = Bs1 + c1*8;

  for(int kk=0; kk<kchunk; kk+=64){
    int k0 = kbeg + kk;
    f32x4 v00a = *(const f32x4*)(gb0 + k0);
    f32x4 v00b = *(const f32x4*)(gb0 + k0 + 4);
    f32x4 v01a = *(const f32x4*)(gb1 + k0);
    f32x4 v01b = *(const f32x4*)(gb1 + k0 + 4);
    f32x4 v10a = *(const f32x4*)(gb0 + k0 + 32);
    f32x4 v10b = *(const f32x4*)(gb0 + k0 + 36);
    f32x4 v11a = *(const f32x4*)(gb1 + k0 + 32);
    f32x4 v11b = *(const f32x4*)(gb1 + k0 + 36);
    uint4 w00 = cvt8(v00a, v00b);
    uint4 w01 = cvt8(v01a, v01b);
    uint4 w10 = cvt8(v10a, v10b);
    uint4 w11 = cvt8(v11a, v11b);
    __syncthreads();
    gld16(la00, ga0 + k0);      gld16(la01, ga1 + k0);
    gld16(la10, ga0 + k0 + 32); gld16(la11, ga1 + k0 + 32);
    *(uint4*)lb00 = w00; *(uint4*)lb01 = w01;
    *(uint4*)lb10 = w10; *(uint4*)lb11 = w11;
    __syncthreads();
    {
      bf16x8 af[4], bfr[4];
      #pragma unroll
      for(int mt=0;mt<4;mt++) af[mt]  = *(const bf16x8*)(As0 + (wm+mt*16+r16)*32 + q*8);
      #pragma unroll
      for(int nt=0;nt<4;nt++) bfr[nt] = *(const bf16x8*)(Bs0 + (wn+nt*16+r16)*32 + q*8);
      #pragma unroll
      for(int mt=0;mt<4;mt++)
        #pragma unroll
        for(int nt=0;nt<4;nt++)
          acc[mt][nt] = __builtin_amdgcn_mfma_f32_16x16x32_bf16(af[mt], bfr[nt], acc[mt][nt], 0,0,0);
    }
    {
      bf16x8 af[4], bfr[4];
      #pragma unroll
      for(int mt=0;mt<4;mt++) af[mt]  = *(const bf16x8*)(As1 + (wm+mt*16+r16)*32 + q*8);
      #pragma unroll
      for(int nt=0;nt<4;nt++) bfr[nt] = *(const bf16x8*)(Bs1 + (wn+nt*16+r16)*32 + q*8);
      #pragma unroll
      for(int mt=0;mt<4;mt++)
        #pragma unroll
        for(int nt=0;nt<4;nt++)
          acc[mt][nt] = __builtin_amdgcn_mfma_f32_16x16x32_bf16(af[mt], bfr[nt], acc[mt][nt], 0,0,0);
    }
  }
  u16* op = yp + (size_t)blockIdx.y*NP*NC;
  #pragma unroll
  for(int mt=0;mt<4;mt++)
    #pragma unroll
    for(int nt=0;nt<4;nt++)
      #pragma unroll
      for(int rr=0;rr<4;rr++){
        int m = m0 + wm + mt*16 + q*4 + rr;
        int n = n0 + wn + nt*16 + r16;
        op[(size_t)m*NC + n] = f2b(acc[mt][nt][rr]);
      }
}

// ------ k_post: sum split-K (bf16), conv_b+BN+relu+residual+LayerNorm ----
__global__ __launch_bounds__(256) void k_post(
    const u16* __restrict__ yp, int nparts,
    const float* __restrict__ x,
    const float* __restrict__ cb, const float* __restrict__ bg,
    const float* __restrict__ bb, const float* __restrict__ bm,
    const float* __restrict__ bv, const float* __restrict__ lg,
    const float* __restrict__ lb, float* __restrict__ out){
  int n = threadIdx.x, bs = blockIdx.x;
  float v[16];
  #pragma unroll
  for(int h=0;h<16;h++) v[h]=0.f;
  for(int p=0;p<nparts;p++){
    const u16* pp = yp + (size_t)p*NP*NC + (size_t)bs*NC + n*16;
    uint4 u0 = ((const uint4*)pp)[0];
    uint4 u1 = ((const uint4*)pp)[1];
    float lo, hi;
    un2(u0.x,lo,hi); v[0]+=lo;  v[1]+=hi;
    un2(u0.y,lo,hi); v[2]+=lo;  v[3]+=hi;
    un2(u0.z,lo,hi); v[4]+=lo;  v[5]+=hi;
    un2(u0.w,lo,hi); v[6]+=lo;  v[7]+=hi;
    un2(u1.x,lo,hi); v[8]+=lo;  v[9]+=hi;
    un2(u1.y,lo,hi); v[10]+=lo; v[11]+=hi;
    un2(u1.z,lo,hi); v[12]+=lo; v[13]+=hi;
    un2(u1.w,lo,hi); v[14]+=lo; v[15]+=hi;
  }
  const float* xp = x + ((size_t)bs*NN + n)*NH;
  float xr[16];
  #pragma unroll
  for(int g=0;g<4;g++) *(f32x4*)&xr[g*4] = ((const f32x4*)xp)[g];

  float mu = 0.f;
  #pragma unroll
  for(int h=0;h<16;h++){
    int co = n*16 + h;
    float t1 = v[h] + cb[co];
    t1 = (t1 - bm[co]) * (1.f/sqrtf(bv[co] + EPSV));
    t1 = t1 * bg[co] + bb[co];
    t1 = fmaxf(t1, 0.f);
    t1 += xr[h];
    v[h] = t1; mu += t1;
  }
  mu *= (1.f/16.f);
  float var = 0.f;
  #pragma unroll
  for(int h=0;h<16;h++){ float d = v[h]-mu; var = fmaf(d,d,var); }
  var *= (1.f/16.f);
  float rs = 1.f/sqrtf(var + EPSV);
  float* op = out + ((size_t)bs*NN + n)*NH;
  #pragma unroll
  for(int h=0;h<16;h++) op[h] = (v[h]-mu)*rs*lg[h] + lb[h];
}

extern "C" void kernel_launch(void* const* d_in, const int* in_sizes, int n_in,
                              void* d_out, int out_size, void* d_ws, size_t ws_size,
                              hipStream_t stream){
  const float* x   = (const float*)d_in[0];
  const float* adj = (const float*)d_in[1];
  const float* W   = (const float*)d_in[2];
  const float* a1  = (const float*)d_in[3];
  const float* a2  = (const float*)d_in[4];
  const float* cw  = (const float*)d_in[5];
  const float* cb  = (const float*)d_in[6];
  const float* bg  = (const float*)d_in[7];
  const float* bb  = (const float*)d_in[8];
  const float* bm  = (const float*)d_in[9];
  const float* bv  = (const float*)d_in[10];
  const float* lg  = (const float*)d_in[11];
  const float* lb  = (const float*)d_in[12];
  float* out = (float*)d_out;

  char* ws = (char*)d_ws;
  const size_t ypb = (size_t)NP*NC*2;                 // 4 MB per split part

  // ---- new path layout ----
  const size_t SP_OFF  = 8192;                        // after am (8 KB)
  const size_t SP_SZ   = (size_t)NB*SROW*NC*2;        // 4.33 MB padded spatial
  const size_t BW_OFF  = SP_OFF + SP_SZ;
  const size_t BW_SZ   = (size_t)NC*NK*2;             // 100.7 MB bf16 weights
  const size_t YP_OFF2 = BW_OFF + BW_SZ;

  u64* am = (u64*)ws;

  int P2 = 0;
  if(ws_size >= YP_OFF2 + 8*ypb)      P2 = 8;
  else if(ws_size >= YP_OFF2 + 4*ypb) P2 = 4;
  else if(ws_size >= YP_OFF2 + 2*ypb) P2 = 2;
  else if(ws_size >= YP_OFF2 + 1*ypb) P2 = 1;

  if(P2){
    u16* Sp = (u16*)(ws + SP_OFF);
    u16* Bw = (u16*)(ws + BW_OFF);
    u16* yp = (u16*)(ws + YP_OFF2);
    hipLaunchKernelGGL(k_adj,  dim3(64),      dim3(256), 0, stream, adj, am, (uint4*)Sp);
    hipLaunchKernelGGL(k_cw,   dim3(NC),      dim3(256), 0, stream, cw, Bw);
    hipLaunchKernelGGL(k_attn, dim3(NP),      dim3(256), 0, stream, x,W,a1,a2,am,Sp);
    hipLaunchKernelGGL(k_gemm, dim3(128,P2),  dim3(256), 0, stream, Sp, Bw, yp, NK/P2);
    hipLaunchKernelGGL(k_post, dim3(NP),      dim3(256), 0, stream, yp,P2,x,cb,bg,bb,bm,bv,lg,lb,out);
  } else {
    // fallback: previous verified path (scatter im2col + fused-cvt GEMM)
    const size_t BT_OFF = 8192;
    const size_t YP_OFF = BT_OFF + (size_t)NP*NK*2;
    int P = 1;
    if(ws_size >= YP_OFF + 8*ypb)      P = 8;
    else if(ws_size >= YP_OFF + 4*ypb) P = 4;
    else if(ws_size >= YP_OFF + 2*ypb) P = 2;
    u16* Bt = (u16*)(ws + BT_OFF);
    u16* yp = (u16*)(ws + YP_OFF);
    hipLaunchKernelGGL(k_adj,    dim3(64),     dim3(256), 0, stream, adj, am, (uint4*)0);
    hipLaunchKernelGGL(k_attn_s, dim3(NP),     dim3(256), 0, stream, x,W,a1,a2,am,Bt);
    hipLaunchKernelGGL(k_gemm_f, dim3(128,P),  dim3(256), 0, stream, Bt, cw, yp, NK/P);
    hipLaunchKernelGGL(k_post,   dim3(NP),     dim3(256), 0, stream, yp,P,x,cb,bg,bb,bm,bv,lg,lb,out);
  }
}

// Round 2
// 448.719 us; speedup vs baseline: 1.0009x; 1.0009x over previous
//
#include <hip/hip_runtime.h>
#include <stdint.h>

#define ALPHA 0.2f
#define EPSV  1e-5f

typedef unsigned short u16;
typedef unsigned int   u32;
typedef unsigned long long u64;
typedef __bf16 bf16x8 __attribute__((ext_vector_type(8)));
typedef __bf16 bf16x2 __attribute__((ext_vector_type(2)));
typedef float  f32x4  __attribute__((ext_vector_type(4)));

#define NB 8
#define NS 64
#define NN 256
#define NF 16
#define NH 16
#define NC 4096     // N*H
#define NK 12288    // NC*3
#define NP 512      // B*S (GEMM M / column count)
#define SROW 66     // padded rows per batch in Sp (1 zero + 64 + 1 zero)

__device__ __forceinline__ u16 f2b(float f){
  u32 u = __float_as_uint(f);
  u32 r = u + 0x7fffu + ((u>>16)&1u);   // round-nearest-even
  return (u16)(r>>16);
}
__device__ __forceinline__ void un2(u32 v, float& lo, float& hi){
  lo = __uint_as_float(v<<16); hi = __uint_as_float(v & 0xffff0000u);
}
__device__ __forceinline__ void gld16(void* lds, const void* g){
  __builtin_amdgcn_global_load_lds((const __attribute__((address_space(1))) u32*)g,
                                   (__attribute__((address_space(3))) u32*)lds, 16, 0, 0);
}
// 8 fp32 -> 8 bf16 (16B)
__device__ __forceinline__ uint4 cvt8(f32x4 a, f32x4 b){
  union { uint4 u; bf16x2 h[4]; } r;
  r.h[0] = (bf16x2){(__bf16)a[0], (__bf16)a[1]};
  r.h[1] = (bf16x2){(__bf16)a[2], (__bf16)a[3]};
  r.h[2] = (bf16x2){(__bf16)b[0], (__bf16)b[1]};
  r.h[3] = (bf16x2){(__bf16)b[2], (__bf16)b[3]};
  return r.u;
}
// 4 fp32 -> 4 bf16 (8B)
__device__ __forceinline__ uint2 cvt4(float a, float b, float c, float d){
  union { uint2 u; bf16x2 h[2]; } r;
  r.h[0] = (bf16x2){(__bf16)a, (__bf16)b};
  r.h[1] = (bf16x2){(__bf16)c, (__bf16)d};
  return r.u;
}

// ------- k_adj: adjacency -> bitmask, + zero Sp pad rows (64 blocks) ------
__global__ __launch_bounds__(256) void k_adj(const float* __restrict__ adj,
                                             u64* __restrict__ am,
                                             uint4* __restrict__ spz){
  int w = threadIdx.x>>6, l = threadIdx.x&63;
  int row = blockIdx.x*4 + w;
  #pragma unroll
  for(int g=0;g<4;g++){
    float v = adj[(size_t)row*NN + g*64 + l];
    u64 m = __ballot(v > 0.f);
    if(l==0) am[row*4+g] = m;
  }
  if(spz){
    // zero the 16 pad rows of Sp: rows b*66+0 and b*66+65, 8192 B each
    int g = blockIdx.x*256 + threadIdx.x;    // 0..16383
    if(g < 8192){
      int r = g>>9;                          // pad row id 0..15
      int b = r>>1;
      size_t prow = (size_t)b*SROW + ((r&1) ? (SROW-1) : 0);
      spz[prow*512 + (g&511)] = (uint4){0,0,0,0};
    }
  }
}

// ------- k_cw: conv_w [co][ci][3] fp32 -> Bw [co][k*4096+ci] bf16 --------
// Pure register transpose: 3 float4 loads cover 4 ci x 3 taps; each output
// tap-quad is a static component swizzle. Coalesced 8B stores per tap.
// No LDS, no bank conflicts (previous version: 16-way-conflicted scalar
// ds_read at stride 3 -> ~5.7x serialization, dominated total runtime).
__global__ __launch_bounds__(256) void k_cw(const float* __restrict__ cw,
                                            u16* __restrict__ Bw){
  int t = threadIdx.x, co = blockIdx.x;
  const float* src = cw + (size_t)co*NK;
  u16* dst = Bw + (size_t)co*NK;
  #pragma unroll
  for(int i=0;i<4;i++){
    int ci0 = (i*256 + t)*4;
    const f32x4* p = (const f32x4*)(src + (size_t)ci0*3);
    f32x4 v0 = p[0];   // (c0,k0)(c0,k1)(c0,k2)(c1,k0)
    f32x4 v1 = p[1];   // (c1,k1)(c1,k2)(c2,k0)(c2,k1)
    f32x4 v2 = p[2];   // (c2,k2)(c3,k0)(c3,k1)(c3,k2)
    uint2 q0 = cvt4(v0[0], v0[3], v1[2], v2[1]);  // tap 0: c0..c3
    uint2 q1 = cvt4(v0[1], v1[0], v1[3], v2[2]);  // tap 1
    uint2 q2 = cvt4(v0[2], v1[1], v2[0], v2[3]);  // tap 2
    *(uint2*)(dst + 0*NC + ci0) = q0;
    *(uint2*)(dst + 1*NC + ci0) = q1;
    *(uint2*)(dst + 2*NC + ci0) = q2;
  }
}

// --- k_attn: per block bs, Wh + masked softmax + spatial -> Sp row (bf16)
// Sp[b][s+1][ci] = spatial[b][s][ci]; rows 0 and 65 per batch are zero pads.
__global__ __launch_bounds__(256) void k_attn(
    const float* __restrict__ x, const float* __restrict__ W,
    const float* __restrict__ a1, const float* __restrict__ a2,
    const u64* __restrict__ am, u16* __restrict__ Sp){
  __shared__ __align__(16) float Ws[NF][NH];
  __shared__ float a1s[NH], a2s[NH];
  __shared__ __align__(16) float Whs[NN][NH];
  __shared__ float f2s[NN];
  int t = threadIdx.x, bs = blockIdx.x;
  int b = bs>>6, s = bs&63;
  Ws[t>>4][t&15] = W[t];
  if(t<NH){ a1s[t]=a1[t]; a2s[t]=a2[t]; }
  u64 mg[4];
  #pragma unroll
  for(int g=0;g<4;g++) mg[g] = am[t*4+g];
  __syncthreads();

  const float* xp = x + ((size_t)bs*NN + t)*NF;
  float xr[16];
  #pragma unroll
  for(int g=0;g<4;g++) *(f32x4*)&xr[g*4] = ((const f32x4*)xp)[g];
  float wh[16];
  #pragma unroll
  for(int h=0;h<16;h++) wh[h]=0.f;
  #pragma unroll
  for(int f=0;f<16;f++){
    float xf = xr[f];
    #pragma unroll
    for(int h=0;h<16;h++) wh[h] = fmaf(xf, Ws[f][h], wh[h]);
  }
  float fi=0.f, s2=0.f;
  #pragma unroll
  for(int h=0;h<16;h++){ fi=fmaf(wh[h],a1s[h],fi); s2=fmaf(wh[h],a2s[h],s2); }
  #pragma unroll
  for(int g=0;g<4;g++) ((f32x4*)Whs[t])[g] = *(f32x4*)&wh[g*4];
  f2s[t] = s2;
  __syncthreads();

  // single-pass masked softmax (no max-subtract: |e| small in fp32)
  float den = 0.f;
  f32x4 a0={0,0,0,0}, a1v={0,0,0,0}, a2v={0,0,0,0}, a3v={0,0,0,0};
  #pragma unroll
  for(int g=0;g<4;g++){
    u64 mm = mg[g];
    for(int jj=0;jj<64;jj++){
      int j = g*64+jj;
      float e = fi + f2s[j];
      e = e > 0.f ? e : ALPHA*e;
      float p = ((mm>>jj)&1ull) ? __expf(e) : 0.f;
      den += p;
      const f32x4* wr = (const f32x4*)Whs[j];
      a0 += wr[0]*p; a1v += wr[1]*p; a2v += wr[2]*p; a3v += wr[3]*p;
    }
  }
  float inv = 1.f/fmaxf(den, 1e-30f);
  f32x4 o0 = a0*inv, o1 = a1v*inv, o2 = a2v*inv, o3 = a3v*inv;

  // coalesced bf16 row store: thread t covers ci = t*16 .. t*16+15 (32 B)
  uint4 w0 = cvt8(o0,o1), w1 = cvt8(o2,o3);
  uint4* op = (uint4*)(Sp + ((size_t)(b*SROW + s + 1))*NC) + t*2;
  op[0] = w0; op[1] = w1;
}

// ------- k_gemm: yp[col][co] = sum_K A[col][K] * Bw[co][K] ---------------
// A row (col = b*64+s) is the contiguous 12288-elem window starting at
// Sp[b][s][0] (tap-major im2col for free). Both operands bf16 via
// global_load_lds (m97 structure). Split-K over blockIdx.y.
__global__ __launch_bounds__(256) void k_gemm(
    const u16* __restrict__ Asp, const u16* __restrict__ Bw,
    u16* __restrict__ yp, int kchunk){
  __shared__ __align__(16) u16 As0[128*32];
  __shared__ __align__(16) u16 As1[128*32];
  __shared__ __align__(16) u16 Bs0[128*32];
  __shared__ __align__(16) u16 Bs1[128*32];
  int t = threadIdx.x;
  int id = blockIdx.x;               // 0..127
  int xr_ = id & 7, q0 = id >> 3;    // xcd residue, remainder
  int mI = q0 & 3, nhi = q0 >> 2;    // m in [0,4), nhi in [0,4)
  int m0 = mI*128, n0 = (nhi*8 + xr_)*128;
  int kbeg = blockIdx.y*kchunk;
  f32x4 acc[4][4];
  #pragma unroll
  for(int i=0;i<4;i++)
    #pragma unroll
    for(int j=0;j<4;j++) acc[i][j] = (f32x4){0,0,0,0};

  int l = t&63, w = t>>6;
  int wm = (w&1)*64, wn = (w>>1)*64;
  int q = l>>4, r16 = l&15;

  int c0 = t, c1 = t+256;
  // chunk c: tile row = c>>2, K-word = c&3 (8 K-elements each).
  int mA0 = m0 + (c0>>2), mA1 = m0 + (c1>>2);
  const u16* ga0 = Asp + (size_t)((mA0>>6)*SROW + (mA0&63))*NC + (c0&3)*8;
  const u16* ga1 = Asp + (size_t)((mA1>>6)*SROW + (mA1&63))*NC + (c1&3)*8;
  const u16* gb0 = Bw  + (size_t)(n0 + (c0>>2))*NK + (c0&3)*8;
  const u16* gb1 = Bw  + (size_t)(n0 + (c1>>2))*NK + (c1&3)*8;
  u16 *la00 = As0 + c0*8, *la01 = As0 + c1*8;
  u16 *la10 = As1 + c0*8, *la11 = As1 + c1*8;
  u16 *lb00 = Bs0 + c0*8, *lb01 = Bs0 + c1*8;
  u16 *lb10 = Bs1 + c0*8, *lb11 = Bs1 + c1*8;

  for(int kk=0; kk<kchunk; kk+=64){
    int k0 = kbeg + kk;
    __syncthreads();                       // prior iter's LDS reads done
    gld16(la00, ga0 + k0);      gld16(la01, ga1 + k0);
    gld16(la10, ga0 + k0 + 32); gld16(la11, ga1 + k0 + 32);
    gld16(lb00, gb0 + k0);      gld16(lb01, gb1 + k0);
    gld16(lb10, gb0 + k0 + 32); gld16(lb11, gb1 + k0 + 32);
    __syncthreads();                       // staging visible (vmcnt drain)
    {
      bf16x8 af[4], bfr[4];
      #pragma unroll
      for(int mt=0;mt<4;mt++) af[mt]  = *(const bf16x8*)(As0 + (wm+mt*16+r16)*32 + q*8);
      #pragma unroll
      for(int nt=0;nt<4;nt++) bfr[nt] = *(const bf16x8*)(Bs0 + (wn+nt*16+r16)*32 + q*8);
      #pragma unroll
      for(int mt=0;mt<4;mt++)
        #pragma unroll
        for(int nt=0;nt<4;nt++)
          acc[mt][nt] = __builtin_amdgcn_mfma_f32_16x16x32_bf16(af[mt], bfr[nt], acc[mt][nt], 0,0,0);
    }
    {
      bf16x8 af[4], bfr[4];
      #pragma unroll
      for(int mt=0;mt<4;mt++) af[mt]  = *(const bf16x8*)(As1 + (wm+mt*16+r16)*32 + q*8);
      #pragma unroll
      for(int nt=0;nt<4;nt++) bfr[nt] = *(const bf16x8*)(Bs1 + (wn+nt*16+r16)*32 + q*8);
      #pragma unroll
      for(int mt=0;mt<4;mt++)
        #pragma unroll
        for(int nt=0;nt<4;nt++)
          acc[mt][nt] = __builtin_amdgcn_mfma_f32_16x16x32_bf16(af[mt], bfr[nt], acc[mt][nt], 0,0,0);
    }
  }
  u16* op = yp + (size_t)blockIdx.y*NP*NC;
  #pragma unroll
  for(int mt=0;mt<4;mt++)
    #pragma unroll
    for(int nt=0;nt<4;nt++)
      #pragma unroll
      for(int rr=0;rr<4;rr++){
        int m = m0 + wm + mt*16 + q*4 + rr;   // C/D: row = quad*4+reg
        int n = n0 + wn + nt*16 + r16;        //      col = lane&15
        op[(size_t)m*NC + n] = f2b(acc[mt][nt][rr]);
      }
}

// ====================== fallback (old) path kernels ======================
// Used only if workspace can't hold the 100 MB transposed weights.
__global__ __launch_bounds__(256) void k_attn_s(
    const float* __restrict__ x, const float* __restrict__ W,
    const float* __restrict__ a1, const float* __restrict__ a2,
    const u64* __restrict__ am, u16* __restrict__ Bt){
  __shared__ __align__(16) float Ws[NF][NH];
  __shared__ float a1s[NH], a2s[NH];
  __shared__ __align__(16) float Whs[NN][NH];
  __shared__ float f2s[NN];
  int t = threadIdx.x, bs = blockIdx.x;
  int b = bs>>6, s = bs&63;
  Ws[t>>4][t&15] = W[t];
  if(t<NH){ a1s[t]=a1[t]; a2s[t]=a2[t]; }
  u64 mg[4];
  #pragma unroll
  for(int g=0;g<4;g++) mg[g] = am[t*4+g];
  __syncthreads();

  const float* xp = x + ((size_t)bs*NN + t)*NF;
  float xr[16];
  #pragma unroll
  for(int g=0;g<4;g++) *(f32x4*)&xr[g*4] = ((const f32x4*)xp)[g];
  float wh[16];
  #pragma unroll
  for(int h=0;h<16;h++) wh[h]=0.f;
  #pragma unroll
  for(int f=0;f<16;f++){
    float xf = xr[f];
    #pragma unroll
    for(int h=0;h<16;h++) wh[h] = fmaf(xf, Ws[f][h], wh[h]);
  }
  float fi=0.f, s2=0.f;
  #pragma unroll
  for(int h=0;h<16;h++){ fi=fmaf(wh[h],a1s[h],fi); s2=fmaf(wh[h],a2s[h],s2); }
  #pragma unroll
  for(int g=0;g<4;g++) ((f32x4*)Whs[t])[g] = *(f32x4*)&wh[g*4];
  f2s[t] = s2;
  __syncthreads();

  float den = 0.f;
  f32x4 a0={0,0,0,0}, a1v={0,0,0,0}, a2v={0,0,0,0}, a3v={0,0,0,0};
  #pragma unroll
  for(int g=0;g<4;g++){
    u64 mm = mg[g];
    for(int jj=0;jj<64;jj++){
      int j = g*64+jj;
      float e = fi + f2s[j];
      e = e > 0.f ? e : ALPHA*e;
      float p = ((mm>>jj)&1ull) ? __expf(e) : 0.f;
      den += p;
      const f32x4* wr = (const f32x4*)Whs[j];
      a0 += wr[0]*p; a1v += wr[1]*p; a2v += wr[2]*p; a3v += wr[3]*p;
    }
  }
  float inv = 1.f/fmaxf(den, 1e-30f);
  float vals[16];
  *(f32x4*)&vals[0]  = a0*inv;  *(f32x4*)&vals[4]  = a1v*inv;
  *(f32x4*)&vals[8]  = a2v*inv; *(f32x4*)&vals[12] = a3v*inv;

  #pragma unroll
  for(int k=0;k<3;k++){
    int cs = s + 1 - k;
    if(cs >= 0 && cs < NS){
      size_t base = ((size_t)(b*NS+cs))*NK + (size_t)t*48 + k;
      #pragma unroll
      for(int h=0;h<16;h++) Bt[base + h*3] = f2b(vals[h]);
    }
  }
  if(s == 0){
    size_t base = ((size_t)(b*NS))*NK + (size_t)t*48;
    #pragma unroll
    for(int h=0;h<16;h++) Bt[base + h*3] = 0;
  }
  if(s == NS-1){
    size_t base = ((size_t)(b*NS+NS-1))*NK + (size_t)t*48 + 2;
    #pragma unroll
    for(int h=0;h<16;h++) Bt[base + h*3] = 0;
  }
}

__global__ __launch_bounds__(256) void k_gemm_f(
    const u16* __restrict__ Abt, const float* __restrict__ Bwf,
    u16* __restrict__ yp, int kchunk){
  __shared__ __align__(16) u16 As0[128*32];
  __shared__ __align__(16) u16 As1[128*32];
  __shared__ __align__(16) u16 Bs0[128*32];
  __shared__ __align__(16) u16 Bs1[128*32];
  int t = threadIdx.x;
  int id = blockIdx.x;
  int xr_ = id & 7, q0 = id >> 3;
  int mI = q0 & 3, nhi = q0 >> 2;
  int m0 = mI*128, n0 = (nhi*8 + xr_)*128;
  int kbeg = blockIdx.y*kchunk;
  f32x4 acc[4][4];
  #pragma unroll
  for(int i=0;i<4;i++)
    #pragma unroll
    for(int j=0;j<4;j++) acc[i][j] = (f32x4){0,0,0,0};

  int l = t&63, w = t>>6;
  int wm = (w&1)*64, wn = (w>>1)*64;
  int q = l>>4, r16 = l&15;

  int c0 = t, c1 = t+256;
  const u16*   ga0 = Abt + (size_t)(m0 + (c0>>2))*NK + (c0&3)*8;
  const u16*   ga1 = Abt + (size_t)(m0 + (c1>>2))*NK + (c1&3)*8;
  const float* gb0 = Bwf + (size_t)(n0 + (c0>>2))*NK + (c0&3)*8;
  const float* gb1 = Bwf + (size_t)(n0 + (c1>>2))*NK + (c1&3)*8;
  u16 *la00 = As0 + c0*8, *la01 = As0 + c1*8;
  u16 *la10 = As1 + c0*8, *la11 = As1 + c1*8;
  u16 *lb00 = Bs0 + c0*8, *lb01 = Bs0 + c1*8;
  u16 *lb10 = Bs1 + c0*8, *lb11 = Bs1 + c1*8;

  for(int kk=0; kk<kchunk; kk+=64){
    int k0 = kbeg + kk;
    f32x4 v00a = *(const f32x4*)(gb0 + k0);
    f32x4 v00b = *(const f32x4*)(gb0 + k0 + 4);
    f32x4 v01a = *(const f32x4*)(gb1 + k0);
    f32x4 v01b = *(const f32x4*)(gb1 + k0 + 4);
    f32x4 v10a = *(const f32x4*)(gb0 + k0 + 32);
    f32x4 v10b = *(const f32x4*)(gb0 + k0 + 36);
    f32x4 v11a = *(const f32x4*)(gb1 + k0 + 32);
    f32x4 v11b = *(const f32x4*)(gb1 + k0 + 36);
    uint4 w00 = cvt8(v00a, v00b);
    uint4 w01 = cvt8(v01a, v01b);
    uint4 w10 = cvt8(v10a, v10b);
    uint4 w11 = cvt8(v11a, v11b);
    __syncthreads();
    gld16(la00, ga0 + k0);      gld16(la01, ga1 + k0);
    gld16(la10, ga0 + k0 + 32); gld16(la11, ga1 + k0 + 32);
    *(uint4*)lb00 = w00; *(uint4*)lb01 = w01;
    *(uint4*)lb10 = w10; *(uint4*)lb11 = w11;
    __syncthreads();
    {
      bf16x8 af[4], bfr[4];
      #pragma unroll
      for(int mt=0;mt<4;mt++) af[mt]  = *(const bf16x8*)(As0 + (wm+mt*16+r16)*32 + q*8);
      #pragma unroll
      for(int nt=0;nt<4;nt++) bfr[nt] = *(const bf16x8*)(Bs0 + (wn+nt*16+r16)*32 + q*8);
      #pragma unroll
      for(int mt=0;mt<4;mt++)
        #pragma unroll
        for(int nt=0;nt<4;nt++)
          acc[mt][nt] = __builtin_amdgcn_mfma_f32_16x16x32_bf16(af[mt], bfr[nt], acc[mt][nt], 0,0,0);
    }
    {
      bf16x8 af[4], bfr[4];
      #pragma unroll
      for(int mt=0;mt<4;mt++) af[mt]  = *(const bf16x8*)(As1 + (wm+mt*16+r16)*32 + q*8);
      #pragma unroll
      for(int nt=0;nt<4;nt++) bfr[nt] = *(const bf16x8*)(Bs1 + (wn+nt*16+r16)*32 + q*8);
      #pragma unroll
      for(int mt=0;mt<4;mt++)
        #pragma unroll
        for(int nt=0;nt<4;nt++)
          acc[mt][nt] = __builtin_amdgcn_mfma_f32_16x16x32_bf16(af[mt], bfr[nt], acc[mt][nt], 0,0,0);
    }
  }
  u16* op = yp + (size_t)blockIdx.y*NP*NC;
  #pragma unroll
  for(int mt=0;mt<4;mt++)
    #pragma unroll
    for(int nt=0;nt<4;nt++)
      #pragma unroll
      for(int rr=0;rr<4;rr++){
        int m = m0 + wm + mt*16 + q*4 + rr;
        int n = n0 + wn + nt*16 + r16;
        op[(size_t)m*NC + n] = f2b(acc[mt][nt][rr]);
      }
}

// ------ k_post: sum split-K (bf16), conv_b+BN+relu+residual+LayerNorm ----
__global__ __launch_bounds__(256) void k_post(
    const u16* __restrict__ yp, int nparts,
    const float* __restrict__ x,
    const float* __restrict__ cb, const float* __restrict__ bg,
    const float* __restrict__ bb, const float* __restrict__ bm,
    const float* __restrict__ bv, const float* __restrict__ lg,
    const float* __restrict__ lb, float* __restrict__ out){
  int n = threadIdx.x, bs = blockIdx.x;
  float v[16];
  #pragma unroll
  for(int h=0;h<16;h++) v[h]=0.f;
  for(int p=0;p<nparts;p++){
    const u16* pp = yp + (size_t)p*NP*NC + (size_t)bs*NC + n*16;
    uint4 u0 = ((const uint4*)pp)[0];
    uint4 u1 = ((const uint4*)pp)[1];
    float lo, hi;
    un2(u0.x,lo,hi); v[0]+=lo;  v[1]+=hi;
    un2(u0.y,lo,hi); v[2]+=lo;  v[3]+=hi;
    un2(u0.z,lo,hi); v[4]+=lo;  v[5]+=hi;
    un2(u0.w,lo,hi); v[6]+=lo;  v[7]+=hi;
    un2(u1.x,lo,hi); v[8]+=lo;  v[9]+=hi;
    un2(u1.y,lo,hi); v[10]+=lo; v[11]+=hi;
    un2(u1.z,lo,hi); v[12]+=lo; v[13]+=hi;
    un2(u1.w,lo,hi); v[14]+=lo; v[15]+=hi;
  }
  const float* xp = x + ((size_t)bs*NN + n)*NH;
  float xr[16];
  #pragma unroll
  for(int g=0;g<4;g++) *(f32x4*)&xr[g*4] = ((const f32x4*)xp)[g];

  float mu = 0.f;
  #pragma unroll
  for(int h=0;h<16;h++){
    int co = n*16 + h;
    float t1 = v[h] + cb[co];
    t1 = (t1 - bm[co]) * (1.f/sqrtf(bv[co] + EPSV));
    t1 = t1 * bg[co] + bb[co];
    t1 = fmaxf(t1, 0.f);
    t1 += xr[h];
    v[h] = t1; mu += t1;
  }
  mu *= (1.f/16.f);
  float var = 0.f;
  #pragma unroll
  for(int h=0;h<16;h++){ float d = v[h]-mu; var = fmaf(d,d,var); }
  var *= (1.f/16.f);
  float rs = 1.f/sqrtf(var + EPSV);
  float* op = out + ((size_t)bs*NN + n)*NH;
  #pragma unroll
  for(int h=0;h<16;h++) op[h] = (v[h]-mu)*rs*lg[h] + lb[h];
}

extern "C" void kernel_launch(void* const* d_in, const int* in_sizes, int n_in,
                              void* d_out, int out_size, void* d_ws, size_t ws_size,
                              hipStream_t stream){
  const float* x   = (const float*)d_in[0];
  const float* adj = (const float*)d_in[1];
  const float* W   = (const float*)d_in[2];
  const float* a1  = (const float*)d_in[3];
  const float* a2  = (const float*)d_in[4];
  const float* cw  = (const float*)d_in[5];
  const float* cb  = (const float*)d_in[6];
  const float* bg  = (const float*)d_in[7];
  const float* bb  = (const float*)d_in[8];
  const float* bm  = (const float*)d_in[9];
  const float* bv  = (const float*)d_in[10];
  const float* lg  = (const float*)d_in[11];
  const float* lb  = (const float*)d_in[12];
  float* out = (float*)d_out;

  char* ws = (char*)d_ws;
  const size_t ypb = (size_t)NP*NC*2;                 // 4 MB per split part

  // ---- new path layout ----
  const size_t SP_OFF  = 8192;                        // after am (8 KB)
  const size_t SP_SZ   = (size_t)NB*SROW*NC*2;        // 4.33 MB padded spatial
  const size_t BW_OFF  = SP_OFF + SP_SZ;
  const size_t BW_SZ   = (size_t)NC*NK*2;             // 100.7 MB bf16 weights
  const size_t YP_OFF2 = BW_OFF + BW_SZ;

  u64* am = (u64*)ws;

  int P2 = 0;
  if(ws_size >= YP_OFF2 + 8*ypb)      P2 = 8;
  else if(ws_size >= YP_OFF2 + 4*ypb) P2 = 4;
  else if(ws_size >= YP_OFF2 + 2*ypb) P2 = 2;
  else if(ws_size >= YP_OFF2 + 1*ypb) P2 = 1;

  if(P2){
    u16* Sp = (u16*)(ws + SP_OFF);
    u16* Bw = (u16*)(ws + BW_OFF);
    u16* yp = (u16*)(ws + YP_OFF2);
    hipLaunchKernelGGL(k_adj,  dim3(64),      dim3(256), 0, stream, adj, am, (uint4*)Sp);
    hipLaunchKernelGGL(k_cw,   dim3(NC),      dim3(256), 0, stream, cw, Bw);
    hipLaunchKernelGGL(k_attn, dim3(NP),      dim3(256), 0, stream, x,W,a1,a2,am,Sp);
    hipLaunchKernelGGL(k_gemm, dim3(128,P2),  dim3(256), 0, stream, Sp, Bw, yp, NK/P2);
    hipLaunchKernelGGL(k_post, dim3(NP),      dim3(256), 0, stream, yp,P2,x,cb,bg,bb,bm,bv,lg,lb,out);
  } else {
    // fallback: previous verified path (scatter im2col + fused-cvt GEMM)
    const size_t BT_OFF = 8192;
    const size_t YP_OFF = BT_OFF + (size_t)NP*NK*2;
    int P = 1;
    if(ws_size >= YP_OFF + 8*ypb)      P = 8;
    else if(ws_size >= YP_OFF + 4*ypb) P = 4;
    else if(ws_size >= YP_OFF + 2*ypb) P = 2;
    u16* Bt = (u16*)(ws + BT_OFF);
    u16* yp = (u16*)(ws + YP_OFF);
    hipLaunchKernelGGL(k_adj,    dim3(64),     dim3(256), 0, stream, adj, am, (uint4*)0);
    hipLaunchKernelGGL(k_attn_s, dim3(NP),     dim3(256), 0, stream, x,W,a1,a2,am,Bt);
    hipLaunchKernelGGL(k_gemm_f, dim3(128,P),  dim3(256), 0, stream, Bt, cw, yp, NK/P);
    hipLaunchKernelGGL(k_post,   dim3(NP),     dim3(256), 0, stream, yp,P,x,cb,bg,bb,bm,bv,lg,lb,out);
  }
}

// Round 3
// 444.240 us; speedup vs baseline: 1.0110x; 1.0101x over previous
//
#include <hip/hip_runtime.h>
#include <stdint.h>

#define ALPHA 0.2f
#define EPSV  1e-5f

typedef unsigned short u16;
typedef unsigned int   u32;
typedef unsigned long long u64;
typedef __bf16 bf16x8 __attribute__((ext_vector_type(8)));
typedef __bf16 bf16x2 __attribute__((ext_vector_type(2)));
typedef float  f32x4  __attribute__((ext_vector_type(4)));

#define NB 8
#define NS 64
#define NN 256
#define NF 16
#define NH 16
#define NC 4096     // N*H
#define NK 12288    // NC*3
#define NP 512      // B*S (GEMM M / column count)
#define SROW 66     // padded rows per batch in Sp (1 zero + 64 + 1 zero)
#define BKT 32      // GEMM K per pipeline tile

__device__ __forceinline__ u16 f2b(float f){
  u32 u = __float_as_uint(f);
  u32 r = u + 0x7fffu + ((u>>16)&1u);   // round-nearest-even
  return (u16)(r>>16);
}
__device__ __forceinline__ void un2(u32 v, float& lo, float& hi){
  lo = __uint_as_float(v<<16); hi = __uint_as_float(v & 0xffff0000u);
}
__device__ __forceinline__ void gld16(void* lds, const void* g){
  __builtin_amdgcn_global_load_lds((const __attribute__((address_space(1))) u32*)g,
                                   (__attribute__((address_space(3))) u32*)lds, 16, 0, 0);
}
// 8 fp32 -> 8 bf16 (16B)
__device__ __forceinline__ uint4 cvt8(f32x4 a, f32x4 b){
  union { uint4 u; bf16x2 h[4]; } r;
  r.h[0] = (bf16x2){(__bf16)a[0], (__bf16)a[1]};
  r.h[1] = (bf16x2){(__bf16)a[2], (__bf16)a[3]};
  r.h[2] = (bf16x2){(__bf16)b[0], (__bf16)b[1]};
  r.h[3] = (bf16x2){(__bf16)b[2], (__bf16)b[3]};
  return r.u;
}
// 4 fp32 -> 4 bf16 (8B)
__device__ __forceinline__ uint2 cvt4(float a, float b, float c, float d){
  union { uint2 u; bf16x2 h[2]; } r;
  r.h[0] = (bf16x2){(__bf16)a, (__bf16)b};
  r.h[1] = (bf16x2){(__bf16)c, (__bf16)d};
  return r.u;
}

// ------- k_adj: adjacency -> bitmask, + zero Sp pad rows (64 blocks) ------
__global__ __launch_bounds__(256) void k_adj(const float* __restrict__ adj,
                                             u64* __restrict__ am,
                                             uint4* __restrict__ spz){
  int w = threadIdx.x>>6, l = threadIdx.x&63;
  int row = blockIdx.x*4 + w;
  #pragma unroll
  for(int g=0;g<4;g++){
    float v = adj[(size_t)row*NN + g*64 + l];
    u64 m = __ballot(v > 0.f);
    if(l==0) am[row*4+g] = m;
  }
  if(spz){
    int g = blockIdx.x*256 + threadIdx.x;    // 0..16383
    if(g < 8192){
      int r = g>>9;                          // pad row id 0..15
      int b = r>>1;
      size_t prow = (size_t)b*SROW + ((r&1) ? (SROW-1) : 0);
      spz[prow*512 + (g&511)] = (uint4){0,0,0,0};
    }
  }
}

// ------- k_cw: conv_w [co][ci][3] fp32 -> Bw [co][k*4096+ci] bf16 --------
__global__ __launch_bounds__(256) void k_cw(const float* __restrict__ cw,
                                            u16* __restrict__ Bw){
  int t = threadIdx.x, co = blockIdx.x;
  const float* src = cw + (size_t)co*NK;
  u16* dst = Bw + (size_t)co*NK;
  #pragma unroll
  for(int i=0;i<4;i++){
    int ci0 = (i*256 + t)*4;
    const f32x4* p = (const f32x4*)(src + (size_t)ci0*3);
    f32x4 v0 = p[0];
    f32x4 v1 = p[1];
    f32x4 v2 = p[2];
    uint2 q0 = cvt4(v0[0], v0[3], v1[2], v2[1]);  // tap 0: c0..c3
    uint2 q1 = cvt4(v0[1], v1[0], v1[3], v2[2]);  // tap 1
    uint2 q2 = cvt4(v0[2], v1[1], v2[0], v2[3]);  // tap 2
    *(uint2*)(dst + 0*NC + ci0) = q0;
    *(uint2*)(dst + 1*NC + ci0) = q1;
    *(uint2*)(dst + 2*NC + ci0) = q2;
  }
}

// --- k_attn: per block bs, Wh + masked softmax + spatial -> Sp row (bf16)
__global__ __launch_bounds__(256) void k_attn(
    const float* __restrict__ x, const float* __restrict__ W,
    const float* __restrict__ a1, const float* __restrict__ a2,
    const u64* __restrict__ am, u16* __restrict__ Sp){
  __shared__ __align__(16) float Ws[NF][NH];
  __shared__ float a1s[NH], a2s[NH];
  __shared__ __align__(16) float Whs[NN][NH];
  __shared__ float f2s[NN];
  int t = threadIdx.x, bs = blockIdx.x;
  int b = bs>>6, s = bs&63;
  Ws[t>>4][t&15] = W[t];
  if(t<NH){ a1s[t]=a1[t]; a2s[t]=a2[t]; }
  u64 mg[4];
  #pragma unroll
  for(int g=0;g<4;g++) mg[g] = am[t*4+g];
  __syncthreads();

  const float* xp = x + ((size_t)bs*NN + t)*NF;
  float xr[16];
  #pragma unroll
  for(int g=0;g<4;g++) *(f32x4*)&xr[g*4] = ((const f32x4*)xp)[g];
  float wh[16];
  #pragma unroll
  for(int h=0;h<16;h++) wh[h]=0.f;
  #pragma unroll
  for(int f=0;f<16;f++){
    float xf = xr[f];
    #pragma unroll
    for(int h=0;h<16;h++) wh[h] = fmaf(xf, Ws[f][h], wh[h]);
  }
  float fi=0.f, s2=0.f;
  #pragma unroll
  for(int h=0;h<16;h++){ fi=fmaf(wh[h],a1s[h],fi); s2=fmaf(wh[h],a2s[h],s2); }
  #pragma unroll
  for(int g=0;g<4;g++) ((f32x4*)Whs[t])[g] = *(f32x4*)&wh[g*4];
  f2s[t] = s2;
  __syncthreads();

  float den = 0.f;
  f32x4 a0={0,0,0,0}, a1v={0,0,0,0}, a2v={0,0,0,0}, a3v={0,0,0,0};
  #pragma unroll
  for(int g=0;g<4;g++){
    u64 mm = mg[g];
    for(int jj=0;jj<64;jj++){
      int j = g*64+jj;
      float e = fi + f2s[j];
      e = e > 0.f ? e : ALPHA*e;
      float p = ((mm>>jj)&1ull) ? __expf(e) : 0.f;
      den += p;
      const f32x4* wr = (const f32x4*)Whs[j];
      a0 += wr[0]*p; a1v += wr[1]*p; a2v += wr[2]*p; a3v += wr[3]*p;
    }
  }
  float inv = 1.f/fmaxf(den, 1e-30f);
  f32x4 o0 = a0*inv, o1 = a1v*inv, o2 = a2v*inv, o3 = a3v*inv;

  uint4 w0 = cvt8(o0,o1), w1 = cvt8(o2,o3);
  uint4* op = (uint4*)(Sp + ((size_t)(b*SROW + s + 1))*NC) + t*2;
  op[0] = w0; op[1] = w1;
}

// ------- k_gemm: 256x256 tile, BK=32, 4-deep counted-vmcnt pipeline ------
__global__ __launch_bounds__(512, 2) void k_gemm(
    const u16* __restrict__ Asp, const u16* __restrict__ Bw,
    u16* __restrict__ yp, int kchunk){
  __shared__ __align__(16) u16 As[4][256*BKT];
  __shared__ __align__(16) u16 Bs[4][256*BKT];
  int t = threadIdx.x;

  int mI, nI, part;
  if(gridDim.y == 8){
    int lin = blockIdx.y*32 + blockIdx.x;   // hw dispatch-linear, 0..255
    int xcd = lin & 7, u = lin >> 3;
    nI = xcd*2 + (u&1); mI = (u>>1)&1; part = u>>2;
  } else {
    mI = blockIdx.x & 1; nI = blockIdx.x >> 1; part = blockIdx.y;
  }
  int m0 = mI*256, n0 = nI*256;
  int kbeg = part*kchunk;
  int NT = kchunk / BKT;

  // staging: 2 A-chunks + 2 B-chunks per thread per tile (16 B each)
  int c0 = t, c1 = 512 + t;
  int rA0 = c0>>2, rA1 = c1>>2;
  int g0 = (c0&3) ^ ((rA0>>1)&3);           // inverse-swizzled src granule
  int g1 = (c1&3) ^ ((rA1>>1)&3);
  int mr0 = m0 + rA0, mr1 = m0 + rA1;
  const u16* gaA0 = Asp + (size_t)((mr0>>6)*SROW + (mr0&63))*NC + kbeg + g0*8;
  const u16* gaA1 = Asp + (size_t)((mr1>>6)*SROW + (mr1&63))*NC + kbeg + g1*8;
  const u16* gbB0 = Bw  + (size_t)(n0 + rA0)*NK + kbeg + g0*8;
  const u16* gbB1 = Bw  + (size_t)(n0 + rA1)*NK + kbeg + g1*8;
  int dA0 = c0*8, dA1 = c1*8;               // linear LDS dest (u16 units)

  int l = t & 63, w = t >> 6;
  int wr = w >> 2, wc = w & 3;              // 2M x 4N waves
  int q = l >> 4, r16 = l & 15;

  int offA[8], offB[4];                     // swizzled read offsets
  #pragma unroll
  for(int mt=0;mt<8;mt++){
    int row = wr*128 + mt*16 + r16;
    offA[mt] = row*BKT + ((q ^ ((row>>1)&3))*8);
  }
  #pragma unroll
  for(int nt=0;nt<4;nt++){
    int row = wc*64 + nt*16 + r16;
    offB[nt] = row*BKT + ((q ^ ((row>>1)&3))*8);
  }

  f32x4 acc[8][4];
  #pragma unroll
  for(int i=0;i<8;i++)
    #pragma unroll
    for(int j=0;j<4;j++) acc[i][j] = (f32x4){0,0,0,0};

  // prologue: stage tiles 0,1,2 (order per tile: A0,A1,B0,B1)
  #pragma unroll
  for(int Tt=0; Tt<3; ++Tt){
    size_t ko = (size_t)Tt*BKT;
    gld16(&As[Tt][dA0], gaA0 + ko); gld16(&As[Tt][dA1], gaA1 + ko);
    gld16(&Bs[Tt][dA0], gbB0 + ko); gld16(&Bs[Tt][dA1], gbB1 + ko);
  }

  #define COMPUTE(BUF)                                                        \
  {                                                                           \
    const u16* ab = As[(BUF)];                                                \
    const u16* bb_ = Bs[(BUF)];                                               \
    bf16x8 af[8], bfr[4];                                                     \
    _Pragma("unroll")                                                         \
    for(int mt=0;mt<8;mt++) af[mt] = *(const bf16x8*)(ab + offA[mt]);         \
    _Pragma("unroll")                                                         \
    for(int nt=0;nt<4;nt++) bfr[nt] = *(const bf16x8*)(bb_ + offB[nt]);       \
    __builtin_amdgcn_s_setprio(1);                                            \
    _Pragma("unroll")                                                         \
    for(int mt=0;mt<8;mt++)                                                   \
      _Pragma("unroll")                                                       \
      for(int nt=0;nt<4;nt++)                                                 \
        acc[mt][nt] = __builtin_amdgcn_mfma_f32_16x16x32_bf16(                \
            af[mt], bfr[nt], acc[mt][nt], 0,0,0);                             \
    __builtin_amdgcn_s_setprio(0);                                            \
  }

  for(int T=0; T<NT-2; ++T){
    __builtin_amdgcn_sched_barrier(0);
    asm volatile("s_waitcnt vmcnt(8)" ::: "memory");   // retire tile T
    __builtin_amdgcn_s_barrier();                      // all waves: T landed
    __builtin_amdgcn_sched_barrier(0);
    if(T+3 < NT){
      int b3 = (T+3)&3;
      size_t ko = (size_t)(T+3)*BKT;
      gld16(&As[b3][dA0], gaA0 + ko); gld16(&As[b3][dA1], gaA1 + ko);
      gld16(&Bs[b3][dA0], gbB0 + ko); gld16(&Bs[b3][dA1], gbB1 + ko);
    }
    COMPUTE(T&3);
  }
  __builtin_amdgcn_sched_barrier(0);
  asm volatile("s_waitcnt vmcnt(4)" ::: "memory");
  __builtin_amdgcn_s_barrier();
  __builtin_amdgcn_sched_barrier(0);
  COMPUTE((NT-2)&3);
  __builtin_amdgcn_sched_barrier(0);
  asm volatile("s_waitcnt vmcnt(0)" ::: "memory");
  __builtin_amdgcn_s_barrier();
  __builtin_amdgcn_sched_barrier(0);
  COMPUTE((NT-1)&3);
  #undef COMPUTE

  u16* op = yp + (size_t)part*NP*NC;
  #pragma unroll
  for(int mt=0;mt<8;mt++)
    #pragma unroll
    for(int nt=0;nt<4;nt++)
      #pragma unroll
      for(int rr=0;rr<4;rr++){
        int m = m0 + wr*128 + mt*16 + q*4 + rr;   // C/D: row = quad*4+reg
        int n = n0 + wc*64 + nt*16 + r16;         //      col = lane&15
        op[(size_t)m*NC + n] = f2b(acc[mt][nt][rr]);
      }
}

// ====================== fallback (old) path kernels ======================
__global__ __launch_bounds__(256) void k_attn_s(
    const float* __restrict__ x, const float* __restrict__ W,
    const float* __restrict__ a1, const float* __restrict__ a2,
    const u64* __restrict__ am, u16* __restrict__ Bt){
  __shared__ __align__(16) float Ws[NF][NH];
  __shared__ float a1s[NH], a2s[NH];
  __shared__ __align__(16) float Whs[NN][NH];
  __shared__ float f2s[NN];
  int t = threadIdx.x, bs = blockIdx.x;
  int b = bs>>6, s = bs&63;
  Ws[t>>4][t&15] = W[t];
  if(t<NH){ a1s[t]=a1[t]; a2s[t]=a2[t]; }
  u64 mg[4];
  #pragma unroll
  for(int g=0;g<4;g++) mg[g] = am[t*4+g];
  __syncthreads();

  const float* xp = x + ((size_t)bs*NN + t)*NF;
  float xr[16];
  #pragma unroll
  for(int g=0;g<4;g++) *(f32x4*)&xr[g*4] = ((const f32x4*)xp)[g];
  float wh[16];
  #pragma unroll
  for(int h=0;h<16;h++) wh[h]=0.f;
  #pragma unroll
  for(int f=0;f<16;f++){
    float xf = xr[f];
    #pragma unroll
    for(int h=0;h<16;h++) wh[h] = fmaf(xf, Ws[f][h], wh[h]);
  }
  float fi=0.f, s2=0.f;
  #pragma unroll
  for(int h=0;h<16;h++){ fi=fmaf(wh[h],a1s[h],fi); s2=fmaf(wh[h],a2s[h],s2); }
  #pragma unroll
  for(int g=0;g<4;g++) ((f32x4*)Whs[t])[g] = *(f32x4*)&wh[g*4];
  f2s[t] = s2;
  __syncthreads();

  float den = 0.f;
  f32x4 a0={0,0,0,0}, a1v={0,0,0,0}, a2v={0,0,0,0}, a3v={0,0,0,0};
  #pragma unroll
  for(int g=0;g<4;g++){
    u64 mm = mg[g];
    for(int jj=0;jj<64;jj++){
      int j = g*64+jj;
      float e = fi + f2s[j];
      e = e > 0.f ? e : ALPHA*e;
      float p = ((mm>>jj)&1ull) ? __expf(e) : 0.f;
      den += p;
      const f32x4* wr = (const f32x4*)Whs[j];
      a0 += wr[0]*p; a1v += wr[1]*p; a2v += wr[2]*p; a3v += wr[3]*p;
    }
  }
  float inv = 1.f/fmaxf(den, 1e-30f);
  float vals[16];
  *(f32x4*)&vals[0]  = a0*inv;  *(f32x4*)&vals[4]  = a1v*inv;
  *(f32x4*)&vals[8]  = a2v*inv; *(f32x4*)&vals[12] = a3v*inv;

  #pragma unroll
  for(int k=0;k<3;k++){
    int cs = s + 1 - k;
    if(cs >= 0 && cs < NS){
      size_t base = ((size_t)(b*NS+cs))*NK + (size_t)t*48 + k;
      #pragma unroll
      for(int h=0;h<16;h++) Bt[base + h*3] = f2b(vals[h]);
    }
  }
  if(s == 0){
    size_t base = ((size_t)(b*NS))*NK + (size_t)t*48;
    #pragma unroll
    for(int h=0;h<16;h++) Bt[base + h*3] = 0;
  }
  if(s == NS-1){
    size_t base = ((size_t)(b*NS+NS-1))*NK + (size_t)t*48 + 2;
    #pragma unroll
    for(int h=0;h<16;h++) Bt[base + h*3] = 0;
  }
}

__global__ __launch_bounds__(256) void k_gemm_f(
    const u16* __restrict__ Abt, const float* __restrict__ Bwf,
    u16* __restrict__ yp, int kchunk){
  __shared__ __align__(16) u16 As0[128*32];
  __shared__ __align__(16) u16 As1[128*32];
  __shared__ __align__(16) u16 Bs0[128*32];
  __shared__ __align__(16) u16 Bs1[128*32];
  int t = threadIdx.x;
  int id = blockIdx.x;
  int xr_ = id & 7, q0 = id >> 3;
  int mI = q0 & 3, nhi = q0 >> 2;
  int m0 = mI*128, n0 = (nhi*8 + xr_)*128;
  int kbeg = blockIdx.y*kchunk;
  f32x4 acc[4][4];
  #pragma unroll
  for(int i=0;i<4;i++)
    #pragma unroll
    for(int j=0;j<4;j++) acc[i][j] = (f32x4){0,0,0,0};

  int l = t&63, w = t>>6;
  int wm = (w&1)*64, wn = (w>>1)*64;
  int q = l>>4, r16 = l&15;

  int c0 = t, c1 = t+256;
  const u16*   ga0 = Abt + (size_t)(m0 + (c0>>2))*NK + (c0&3)*8;
  const u16*   ga1 = Abt + (size_t)(m0 + (c1>>2))*NK + (c1&3)*8;
  const float* gb0 = Bwf + (size_t)(n0 + (c0>>2))*NK + (c0&3)*8;
  const float* gb1 = Bwf + (size_t)(n0 + (c1>>2))*NK + (c1&3)*8;
  u16 *la00 = As0 + c0*8, *la01 = As0 + c1*8;
  u16 *la10 = As1 + c0*8, *la11 = As1 + c1*8;
  u16 *lb00 = Bs0 + c0*8, *lb01 = Bs0 + c1*8;
  u16 *lb10 = Bs1 + c0*8, *lb11 = Bs1 + c1*8;

  for(int kk=0; kk<kchunk; kk+=64){
    int k0 = kbeg + kk;
    f32x4 v00a = *(const f32x4*)(gb0 + k0);
    f32x4 v00b = *(const f32x4*)(gb0 + k0 + 4);
    f32x4 v01a = *(const f32x4*)(gb1 + k0);
    f32x4 v01b = *(const f32x4*)(gb1 + k0 + 4);
    f32x4 v10a = *(const f32x4*)(gb0 + k0 + 32);
    f32x4 v10b = *(const f32x4*)(gb0 + k0 + 36);
    f32x4 v11a = *(const f32x4*)(gb1 + k0 + 32);
    f32x4 v11b = *(const f32x4*)(gb1 + k0 + 36);
    uint4 w00 = cvt8(v00a, v00b);
    uint4 w01 = cvt8(v01a, v01b);
    uint4 w10 = cvt8(v10a, v10b);
    uint4 w11 = cvt8(v11a, v11b);
    __syncthreads();
    gld16(la00, ga0 + k0);      gld16(la01, ga1 + k0);
    gld16(la10, ga0 + k0 + 32); gld16(la11, ga1 + k0 + 32);
    *(uint4*)lb00 = w00; *(uint4*)lb01 = w01;
    *(uint4*)lb10 = w10; *(uint4*)lb11 = w11;
    __syncthreads();
    {
      bf16x8 af[4], bfr[4];
      #pragma unroll
      for(int mt=0;mt<4;mt++) af[mt]  = *(const bf16x8*)(As0 + (wm+mt*16+r16)*32 + q*8);
      #pragma unroll
      for(int nt=0;nt<4;nt++) bfr[nt] = *(const bf16x8*)(Bs0 + (wn+nt*16+r16)*32 + q*8);
      #pragma unroll
      for(int mt=0;mt<4;mt++)
        #pragma unroll
        for(int nt=0;nt<4;nt++)
          acc[mt][nt] = __builtin_amdgcn_mfma_f32_16x16x32_bf16(af[mt], bfr[nt], acc[mt][nt], 0,0,0);
    }
    {
      bf16x8 af[4], bfr[4];
      #pragma unroll
      for(int mt=0;mt<4;mt++) af[mt]  = *(const bf16x8*)(As1 + (wm+mt*16+r16)*32 + q*8);
      #pragma unroll
      for(int nt=0;nt<4;nt++) bfr[nt] = *(const bf16x8*)(Bs1 + (wn+nt*16+r16)*32 + q*8);
      #pragma unroll
      for(int mt=0;mt<4;mt++)
        #pragma unroll
        for(int nt=0;nt<4;nt++)
          acc[mt][nt] = __builtin_amdgcn_mfma_f32_16x16x32_bf16(af[mt], bfr[nt], acc[mt][nt], 0,0,0);
    }
  }
  u16* op = yp + (size_t)blockIdx.y*NP*NC;
  #pragma unroll
  for(int mt=0;mt<4;mt++)
    #pragma unroll
    for(int nt=0;nt<4;nt++)
      #pragma unroll
      for(int rr=0;rr<4;rr++){
        int m = m0 + wm + mt*16 + q*4 + rr;
        int n = n0 + wn + nt*16 + r16;
        op[(size_t)m*NC + n] = f2b(acc[mt][nt][rr]);
      }
}

// ------ k_post: sum split-K (bf16), conv_b+BN+relu+residual+LayerNorm ----
__global__ __launch_bounds__(256) void k_post(
    const u16* __restrict__ yp, int nparts,
    const float* __restrict__ x,
    const float* __restrict__ cb, const float* __restrict__ bg,
    const float* __restrict__ bb, const float* __restrict__ bm,
    const float* __restrict__ bv, const float* __restrict__ lg,
    const float* __restrict__ lb, float* __restrict__ out){
  int n = threadIdx.x, bs = blockIdx.x;
  float v[16];
  #pragma unroll
  for(int h=0;h<16;h++) v[h]=0.f;
  for(int p=0;p<nparts;p++){
    const u16* pp = yp + (size_t)p*NP*NC + (size_t)bs*NC + n*16;
    uint4 u0 = ((const uint4*)pp)[0];
    uint4 u1 = ((const uint4*)pp)[1];
    float lo, hi;
    un2(u0.x,lo,hi); v[0]+=lo;  v[1]+=hi;
    un2(u0.y,lo,hi); v[2]+=lo;  v[3]+=hi;
    un2(u0.z,lo,hi); v[4]+=lo;  v[5]+=hi;
    un2(u0.w,lo,hi); v[6]+=lo;  v[7]+=hi;
    un2(u1.x,lo,hi); v[8]+=lo;  v[9]+=hi;
    un2(u1.y,lo,hi); v[10]+=lo; v[11]+=hi;
    un2(u1.z,lo,hi); v[12]+=lo; v[13]+=hi;
    un2(u1.w,lo,hi); v[14]+=lo; v[15]+=hi;
  }
  const float* xp = x + ((size_t)bs*NN + n)*NH;
  float xr[16];
  #pragma unroll
  for(int g=0;g<4;g++) *(f32x4*)&xr[g*4] = ((const f32x4*)xp)[g];

  float mu = 0.f;
  #pragma unroll
  for(int h=0;h<16;h++){
    int co = n*16 + h;
    float t1 = v[h] + cb[co];
    t1 = (t1 - bm[co]) * (1.f/sqrtf(bv[co] + EPSV));
    t1 = t1 * bg[co] + bb[co];
    t1 = fmaxf(t1, 0.f);
    t1 += xr[h];
    v[h] = t1; mu += t1;
  }
  mu *= (1.f/16.f);
  float var = 0.f;
  #pragma unroll
  for(int h=0;h<16;h++){ float d = v[h]-mu; var = fmaf(d,d,var); }
  var *= (1.f/16.f);
  float rs = 1.f/sqrtf(var + EPSV);
  float* op = out + ((size_t)bs*NN + n)*NH;
  #pragma unroll
  for(int h=0;h<16;h++) op[h] = (v[h]-mu)*rs*lg[h] + lb[h];
}

extern "C" void kernel_launch(void* const* d_in, const int* in_sizes, int n_in,
                              void* d_out, int out_size, void* d_ws, size_t ws_size,
                              hipStream_t stream){
  const float* x   = (const float*)d_in[0];
  const float* adj = (const float*)d_in[1];
  const float* W   = (const float*)d_in[2];
  const float* a1  = (const float*)d_in[3];
  const float* a2  = (const float*)d_in[4];
  const float* cw  = (const float*)d_in[5];
  const float* cb  = (const float*)d_in[6];
  const float* bg  = (const float*)d_in[7];
  const float* bb  = (const float*)d_in[8];
  const float* bm  = (const float*)d_in[9];
  const float* bv  = (const float*)d_in[10];
  const float* lg  = (const float*)d_in[11];
  const float* lb  = (const float*)d_in[12];
  float* out = (float*)d_out;

  char* ws = (char*)d_ws;
  const size_t ypb = (size_t)NP*NC*2;                 // 4 MB per split part

  const size_t SP_OFF  = 8192;                        // after am (8 KB)
  const size_t SP_SZ   = (size_t)NB*SROW*NC*2;        // 4.33 MB padded spatial
  const size_t BW_OFF  = SP_OFF + SP_SZ;
  const size_t BW_SZ   = (size_t)NC*NK*2;             // 100.7 MB bf16 weights
  const size_t YP_OFF2 = BW_OFF + BW_SZ;

  u64* am = (u64*)ws;

  int P2 = 0;
  if(ws_size >= YP_OFF2 + 8*ypb)      P2 = 8;
  else if(ws_size >= YP_OFF2 + 4*ypb) P2 = 4;
  else if(ws_size >= YP_OFF2 + 2*ypb) P2 = 2;
  else if(ws_size >= YP_OFF2 + 1*ypb) P2 = 1;

  if(P2){
    u16* Sp = (u16*)(ws + SP_OFF);
    u16* Bw = (u16*)(ws + BW_OFF);
    u16* yp = (u16*)(ws + YP_OFF2);
    hipLaunchKernelGGL(k_adj,  dim3(64),      dim3(256), 0, stream, adj, am, (uint4*)Sp);
    hipLaunchKernelGGL(k_cw,   dim3(NC),      dim3(256), 0, stream, cw, Bw);
    hipLaunchKernelGGL(k_attn, dim3(NP),      dim3(256), 0, stream, x,W,a1,a2,am,Sp);
    hipLaunchKernelGGL(k_gemm, dim3(32,P2),   dim3(512), 0, stream, Sp, Bw, yp, NK/P2);
    hipLaunchKernelGGL(k_post, dim3(NP),      dim3(256), 0, stream, yp,P2,x,cb,bg,bb,bm,bv,lg,lb,out);
  } else {
    const size_t BT_OFF = 8192;
    const size_t YP_OFF = BT_OFF + (size_t)NP*NK*2;
    int P = 1;
    if(ws_size >= YP_OFF + 8*ypb)      P = 8;
    else if(ws_size >= YP_OFF + 4*ypb) P = 4;
    else if(ws_size >= YP_OFF + 2*ypb) P = 2;
    u16* Bt = (u16*)(ws + BT_OFF);
    u16* yp = (u16*)(ws + YP_OFF);
    hipLaunchKernelGGL(k_adj,    dim3(64),     dim3(256), 0, stream, adj, am, (uint4*)0);
    hipLaunchKernelGGL(k_attn_s, dim3(NP),     dim3(256), 0, stream, x,W,a1,a2,am,Bt);
    hipLaunchKernelGGL(k_gemm_f, dim3(128,P),  dim3(256), 0, stream, Bt, cw, yp, NK/P);
    hipLaunchKernelGGL(k_post,   dim3(NP),     dim3(256), 0, stream, yp,P,x,cb,bg,bb,bm,bv,lg,lb,out);
  }
}

// Round 4
// 416.662 us; speedup vs baseline: 1.0779x; 1.0662x over previous
//
#include <hip/hip_runtime.h>
#include <stdint.h>

#define ALPHA 0.2f
#define EPSV  1e-5f

typedef unsigned short u16;
typedef unsigned int   u32;
typedef unsigned long long u64;
typedef __bf16 bf16x8 __attribute__((ext_vector_type(8)));
typedef __bf16 bf16x2 __attribute__((ext_vector_type(2)));
typedef float  f32x4  __attribute__((ext_vector_type(4)));

#define NB 8
#define NS 64
#define NN 256
#define NF 16
#define NH 16
#define NC 4096     // N*H
#define NK 12288    // NC*3
#define NP 512      // B*S (GEMM M / column count)
#define SROW 66     // padded rows per batch in Sp (1 zero + 64 + 1 zero)
#define BKT 32      // GEMM K per pipeline tile

__device__ __forceinline__ u16 f2b(float f){
  u32 u = __float_as_uint(f);
  u32 r = u + 0x7fffu + ((u>>16)&1u);   // round-nearest-even
  return (u16)(r>>16);
}
__device__ __forceinline__ void un2(u32 v, float& lo, float& hi){
  lo = __uint_as_float(v<<16); hi = __uint_as_float(v & 0xffff0000u);
}
__device__ __forceinline__ void gld16(void* lds, const void* g){
  __builtin_amdgcn_global_load_lds((const __attribute__((address_space(1))) u32*)g,
                                   (__attribute__((address_space(3))) u32*)lds, 16, 0, 0);
}
// 8 fp32 -> 8 bf16 (16B)
__device__ __forceinline__ uint4 cvt8(f32x4 a, f32x4 b){
  union { uint4 u; bf16x2 h[4]; } r;
  r.h[0] = (bf16x2){(__bf16)a[0], (__bf16)a[1]};
  r.h[1] = (bf16x2){(__bf16)a[2], (__bf16)a[3]};
  r.h[2] = (bf16x2){(__bf16)b[0], (__bf16)b[1]};
  r.h[3] = (bf16x2){(__bf16)b[2], (__bf16)b[3]};
  return r.u;
}

// ------- k_adj: adjacency -> bitmask, + zero Sp pad rows (64 blocks) ------
__global__ __launch_bounds__(256) void k_adj(const float* __restrict__ adj,
                                             u64* __restrict__ am,
                                             uint4* __restrict__ spz){
  int w = threadIdx.x>>6, l = threadIdx.x&63;
  int row = blockIdx.x*4 + w;
  #pragma unroll
  for(int g=0;g<4;g++){
    float v = adj[(size_t)row*NN + g*64 + l];
    u64 m = __ballot(v > 0.f);
    if(l==0) am[row*4+g] = m;
  }
  if(spz){
    int g = blockIdx.x*256 + threadIdx.x;    // 0..16383
    if(g < 8192){
      int r = g>>9;                          // pad row id 0..15
      int b = r>>1;
      size_t prow = (size_t)b*SROW + ((r&1) ? (SROW-1) : 0);
      spz[prow*512 + (g&511)] = (uint4){0,0,0,0};
    }
  }
}

// --- k_attn: per block bs, Wh + masked softmax + spatial -> Sp row (bf16)
__global__ __launch_bounds__(256) void k_attn(
    const float* __restrict__ x, const float* __restrict__ W,
    const float* __restrict__ a1, const float* __restrict__ a2,
    const u64* __restrict__ am, u16* __restrict__ Sp){
  __shared__ __align__(16) float Ws[NF][NH];
  __shared__ float a1s[NH], a2s[NH];
  __shared__ __align__(16) float Whs[NN][NH];
  __shared__ float f2s[NN];
  int t = threadIdx.x, bs = blockIdx.x;
  int b = bs>>6, s = bs&63;
  Ws[t>>4][t&15] = W[t];
  if(t<NH){ a1s[t]=a1[t]; a2s[t]=a2[t]; }
  u64 mg[4];
  #pragma unroll
  for(int g=0;g<4;g++) mg[g] = am[t*4+g];
  __syncthreads();

  const float* xp = x + ((size_t)bs*NN + t)*NF;
  float xr[16];
  #pragma unroll
  for(int g=0;g<4;g++) *(f32x4*)&xr[g*4] = ((const f32x4*)xp)[g];
  float wh[16];
  #pragma unroll
  for(int h=0;h<16;h++) wh[h]=0.f;
  #pragma unroll
  for(int f=0;f<16;f++){
    float xf = xr[f];
    #pragma unroll
    for(int h=0;h<16;h++) wh[h] = fmaf(xf, Ws[f][h], wh[h]);
  }
  float fi=0.f, s2=0.f;
  #pragma unroll
  for(int h=0;h<16;h++){ fi=fmaf(wh[h],a1s[h],fi); s2=fmaf(wh[h],a2s[h],s2); }
  #pragma unroll
  for(int g=0;g<4;g++) ((f32x4*)Whs[t])[g] = *(f32x4*)&wh[g*4];
  f2s[t] = s2;
  __syncthreads();

  float den = 0.f;
  f32x4 a0={0,0,0,0}, a1v={0,0,0,0}, a2v={0,0,0,0}, a3v={0,0,0,0};
  #pragma unroll
  for(int g=0;g<4;g++){
    u64 mm = mg[g];
    for(int jj=0;jj<64;jj++){
      int j = g*64+jj;
      float e = fi + f2s[j];
      e = e > 0.f ? e : ALPHA*e;
      float p = ((mm>>jj)&1ull) ? __expf(e) : 0.f;
      den += p;
      const f32x4* wr = (const f32x4*)Whs[j];
      a0 += wr[0]*p; a1v += wr[1]*p; a2v += wr[2]*p; a3v += wr[3]*p;
    }
  }
  float inv = 1.f/fmaxf(den, 1e-30f);
  f32x4 o0 = a0*inv, o1 = a1v*inv, o2 = a2v*inv, o3 = a3v*inv;

  uint4 w0 = cvt8(o0,o1), w1 = cvt8(o2,o3);
  uint4* op = (uint4*)(Sp + ((size_t)(b*SROW + s + 1))*NC) + t*2;
  op[0] = w0; op[1] = w1;
}

// ------- k_i2c: Sp rows -> ci-major im2col Bt[col][ci*3+k] (bf16) --------
// Bt[col][ci*3+k] = Sp[b][s+k][ci]  (padded rows give the conv zero pads).
// Reads 3x32B per thread (coalesced), register-interleave, writes 96B
// contiguous per thread. ~25 MB total traffic, mostly L2.
__global__ __launch_bounds__(256) void k_i2c(const u16* __restrict__ Sp,
                                             u16* __restrict__ Bt){
  int t = threadIdx.x, col = blockIdx.x;
  int b = col>>6, s = col&63;
  const u16* r0 = Sp + ((size_t)(b*SROW + s))*NC + t*16;
  union { uint4 q[2]; u16 h[16]; } a0, a1, a2;
  a0.q[0]=((const uint4*)r0)[0];        a0.q[1]=((const uint4*)r0)[1];
  a1.q[0]=((const uint4*)(r0+NC))[0];   a1.q[1]=((const uint4*)(r0+NC))[1];
  a2.q[0]=((const uint4*)(r0+2*NC))[0]; a2.q[1]=((const uint4*)(r0+2*NC))[1];
  union { uint4 q[6]; u16 h[48]; } o;
  #pragma unroll
  for(int i=0;i<16;i++){
    o.h[3*i]   = a0.h[i];
    o.h[3*i+1] = a1.h[i];
    o.h[3*i+2] = a2.h[i];
  }
  uint4* dst = (uint4*)(Bt + (size_t)col*NK + t*48);
  #pragma unroll
  for(int j=0;j<6;j++) dst[j] = o.q[j];
}

// ------- k_gemm: 256x256 tile, BK=32, counted-vmcnt pipeline -------------
// A = Bt bf16 (ci-major im2col), staged 2-ahead via global_load_lds.
// B = conv_w fp32 NATIVE layout [co][ci*3+k] (no transform kernel!),
//     reg-loaded 2-ahead, cvt->bf16, swizzle-ds_written 1-ahead (T14 split).
// Steady state: 8 VMEM in flight; s_waitcnt vmcnt(2) retires {A(T),B(T+1)}.
// LDS: 3 x (A 16KB + B 16KB) = 96 KB. XOR granule swizzle kills bank
// conflicts (A: inverse swizzle on global source; B: swizzled ds_write).
__global__ __launch_bounds__(512, 2) void k_gemm(
    const u16* __restrict__ Abt, const float* __restrict__ Bwf,
    u16* __restrict__ yp, int kchunk){
  __shared__ __align__(16) u16 As[3][256*BKT];
  __shared__ __align__(16) u16 Bs[3][256*BKT];
  int t = threadIdx.x;

  int mI, nI, part;
  if(gridDim.y == 8){
    int lin = blockIdx.y*32 + blockIdx.x;   // hw dispatch-linear, 0..255
    int xcd = lin & 7, u = lin >> 3;
    nI = xcd*2 + (u&1); mI = (u>>1)&1; part = u>>2;
  } else {
    mI = blockIdx.x & 1; nI = blockIdx.x >> 1; part = blockIdx.y;
  }
  int m0 = mI*256, n0 = nI*256;
  int kbeg = part*kchunk;
  int NT = kchunk / BKT;                    // even for P in {1,2,4,8}

  // ---- A staging: 2 chunks (16B) per thread per tile via gld16 ----
  int c0 = t, c1 = 512 + t;
  int rA0 = c0>>2, rA1 = c1>>2;             // rows 0..127 / 128..255
  int g0 = (c0&3) ^ ((rA0>>1)&3);           // inverse-swizzled src granule
  int g1 = (c1&3) ^ ((rA1>>1)&3);
  const u16* gaA0 = Abt + (size_t)(m0 + rA0)*NK + kbeg + g0*8;
  const u16* gaA1 = Abt + (size_t)(m0 + rA1)*NK + kbeg + g1*8;
  int dA0 = c0*8, dA1 = c1*8;               // linear LDS dest (u16 units)

  // ---- B staging: 16 fp32 per thread per tile (reg), cvt, ds_write ----
  int rowB = t>>1, halfB = t&1;
  const float* gbB = Bwf + (size_t)(n0 + rowB)*NK + kbeg + halfB*16;
  int gB0 = (halfB*2 + 0) ^ ((rowB>>1)&3);  // swizzled write granules
  int gB1 = (halfB*2 + 1) ^ ((rowB>>1)&3);
  int dB0 = rowB*BKT + gB0*8, dB1 = rowB*BKT + gB1*8;

  // ---- wave decomposition: 8 waves = 2M x 4N, per-wave out 128x64 ----
  int l = t & 63, w = t >> 6;
  int wr = w >> 2, wc = w & 3;
  int q = l >> 4, r16 = l & 15;

  int offA[8], offB[4];                     // swizzled read offsets
  #pragma unroll
  for(int mt=0;mt<8;mt++){
    int row = wr*128 + mt*16 + r16;
    offA[mt] = row*BKT + ((q ^ ((row>>1)&3))*8);
  }
  #pragma unroll
  for(int nt=0;nt<4;nt++){
    int row = wc*64 + nt*16 + r16;
    offB[nt] = row*BKT + ((q ^ ((row>>1)&3))*8);
  }

  f32x4 acc[8][4];
  #pragma unroll
  for(int i=0;i<8;i++)
    #pragma unroll
    for(int j=0;j<4;j++) acc[i][j] = (f32x4){0,0,0,0};

  f32x4 rb0[4], rb1[4];

  #define ISSUE_A(TT) { size_t ko=(size_t)(TT)*BKT; int bf=(TT)%3;            \
    gld16(&As[bf][dA0], gaA0+ko); gld16(&As[bf][dA1], gaA1+ko); }
  #define LOAD_B(TT, R) { size_t ko=(size_t)(TT)*BKT;                         \
    R[0]=*(const f32x4*)(gbB+ko);    R[1]=*(const f32x4*)(gbB+ko+4);          \
    R[2]=*(const f32x4*)(gbB+ko+8);  R[3]=*(const f32x4*)(gbB+ko+12); }
  #define DSW_B(TT, R) { int bf=(TT)%3;                                       \
    uint4 w0_=cvt8(R[0],R[1]), w1_=cvt8(R[2],R[3]);                           \
    *(uint4*)&Bs[bf][dB0] = w0_; *(uint4*)&Bs[bf][dB1] = w1_; }
  #define COMPUTE(BUF)                                                        \
  {                                                                           \
    const u16* ab  = As[(BUF)];                                               \
    const u16* bb_ = Bs[(BUF)];                                               \
    bf16x8 af[8], bfr[4];                                                     \
    _Pragma("unroll")                                                         \
    for(int mt=0;mt<8;mt++) af[mt] = *(const bf16x8*)(ab + offA[mt]);         \
    _Pragma("unroll")                                                         \
    for(int nt=0;nt<4;nt++) bfr[nt] = *(const bf16x8*)(bb_ + offB[nt]);       \
    __builtin_amdgcn_s_setprio(1);                                            \
    _Pragma("unroll")                                                         \
    for(int mt=0;mt<8;mt++)                                                   \
      _Pragma("unroll")                                                       \
      for(int nt=0;nt<4;nt++)                                                 \
        acc[mt][nt] = __builtin_amdgcn_mfma_f32_16x16x32_bf16(                \
            af[mt], bfr[nt], acc[mt][nt], 0,0,0);                             \
    __builtin_amdgcn_s_setprio(0);                                            \
  }

  // prologue: A(0) staged+drained; B(0) written; in-flight = [B(1),A(1)]
  ISSUE_A(0);
  LOAD_B(0, rb0);
  asm volatile("s_waitcnt vmcnt(0)" ::: "memory");
  __builtin_amdgcn_sched_barrier(0);
  DSW_B(0, rb0);
  LOAD_B(1, rb0);
  ISSUE_A(1);
  asm volatile("s_waitcnt lgkmcnt(0)" ::: "memory");
  __builtin_amdgcn_s_barrier();
  __builtin_amdgcn_sched_barrier(0);

  #define GITER(T, RCUR, RNXT) {                                              \
    if((T) < NT-1){ asm volatile("s_waitcnt vmcnt(2)" ::: "memory"); }        \
    else          { asm volatile("s_waitcnt vmcnt(0)" ::: "memory"); }        \
    __builtin_amdgcn_sched_barrier(0);                                        \
    if((T) < NT-1){ DSW_B((T)+1, RCUR); }                                     \
    asm volatile("s_waitcnt lgkmcnt(0)" ::: "memory");                        \
    __builtin_amdgcn_s_barrier();                                             \
    __builtin_amdgcn_sched_barrier(0);                                        \
    if((T)+2 < NT){ LOAD_B((T)+2, RNXT); ISSUE_A((T)+2); }                    \
    COMPUTE((T)%3);                                                           \
  }

  for(int T=0; T<NT; T+=2){
    GITER(T,   rb0, rb1);
    GITER(T+1, rb1, rb0);
  }
  #undef GITER
  #undef COMPUTE
  #undef DSW_B
  #undef LOAD_B
  #undef ISSUE_A

  u16* op = yp + (size_t)part*NP*NC;
  #pragma unroll
  for(int mt=0;mt<8;mt++)
    #pragma unroll
    for(int nt=0;nt<4;nt++)
      #pragma unroll
      for(int rr=0;rr<4;rr++){
        int m = m0 + wr*128 + mt*16 + q*4 + rr;   // C/D: row = quad*4+reg
        int n = n0 + wc*64 + nt*16 + r16;         //      col = lane&15
        op[(size_t)m*NC + n] = f2b(acc[mt][nt][rr]);
      }
}

// ====================== fallback (old) path kernels ======================
__global__ __launch_bounds__(256) void k_attn_s(
    const float* __restrict__ x, const float* __restrict__ W,
    const float* __restrict__ a1, const float* __restrict__ a2,
    const u64* __restrict__ am, u16* __restrict__ Bt){
  __shared__ __align__(16) float Ws[NF][NH];
  __shared__ float a1s[NH], a2s[NH];
  __shared__ __align__(16) float Whs[NN][NH];
  __shared__ float f2s[NN];
  int t = threadIdx.x, bs = blockIdx.x;
  int b = bs>>6, s = bs&63;
  Ws[t>>4][t&15] = W[t];
  if(t<NH){ a1s[t]=a1[t]; a2s[t]=a2[t]; }
  u64 mg[4];
  #pragma unroll
  for(int g=0;g<4;g++) mg[g] = am[t*4+g];
  __syncthreads();

  const float* xp = x + ((size_t)bs*NN + t)*NF;
  float xr[16];
  #pragma unroll
  for(int g=0;g<4;g++) *(f32x4*)&xr[g*4] = ((const f32x4*)xp)[g];
  float wh[16];
  #pragma unroll
  for(int h=0;h<16;h++) wh[h]=0.f;
  #pragma unroll
  for(int f=0;f<16;f++){
    float xf = xr[f];
    #pragma unroll
    for(int h=0;h<16;h++) wh[h] = fmaf(xf, Ws[f][h], wh[h]);
  }
  float fi=0.f, s2=0.f;
  #pragma unroll
  for(int h=0;h<16;h++){ fi=fmaf(wh[h],a1s[h],fi); s2=fmaf(wh[h],a2s[h],s2); }
  #pragma unroll
  for(int g=0;g<4;g++) ((f32x4*)Whs[t])[g] = *(f32x4*)&wh[g*4];
  f2s[t] = s2;
  __syncthreads();

  float den = 0.f;
  f32x4 a0={0,0,0,0}, a1v={0,0,0,0}, a2v={0,0,0,0}, a3v={0,0,0,0};
  #pragma unroll
  for(int g=0;g<4;g++){
    u64 mm = mg[g];
    for(int jj=0;jj<64;jj++){
      int j = g*64+jj;
      float e = fi + f2s[j];
      e = e > 0.f ? e : ALPHA*e;
      float p = ((mm>>jj)&1ull) ? __expf(e) : 0.f;
      den += p;
      const f32x4* wr = (const f32x4*)Whs[j];
      a0 += wr[0]*p; a1v += wr[1]*p; a2v += wr[2]*p; a3v += wr[3]*p;
    }
  }
  float inv = 1.f/fmaxf(den, 1e-30f);
  float vals[16];
  *(f32x4*)&vals[0]  = a0*inv;  *(f32x4*)&vals[4]  = a1v*inv;
  *(f32x4*)&vals[8]  = a2v*inv; *(f32x4*)&vals[12] = a3v*inv;

  #pragma unroll
  for(int k=0;k<3;k++){
    int cs = s + 1 - k;
    if(cs >= 0 && cs < NS){
      size_t base = ((size_t)(b*NS+cs))*NK + (size_t)t*48 + k;
      #pragma unroll
      for(int h=0;h<16;h++) Bt[base + h*3] = f2b(vals[h]);
    }
  }
  if(s == 0){
    size_t base = ((size_t)(b*NS))*NK + (size_t)t*48;
    #pragma unroll
    for(int h=0;h<16;h++) Bt[base + h*3] = 0;
  }
  if(s == NS-1){
    size_t base = ((size_t)(b*NS+NS-1))*NK + (size_t)t*48 + 2;
    #pragma unroll
    for(int h=0;h<16;h++) Bt[base + h*3] = 0;
  }
}

__global__ __launch_bounds__(256) void k_gemm_f(
    const u16* __restrict__ Abt, const float* __restrict__ Bwf,
    u16* __restrict__ yp, int kchunk){
  __shared__ __align__(16) u16 As0[128*32];
  __shared__ __align__(16) u16 As1[128*32];
  __shared__ __align__(16) u16 Bs0[128*32];
  __shared__ __align__(16) u16 Bs1[128*32];
  int t = threadIdx.x;
  int id = blockIdx.x;
  int xr_ = id & 7, q0 = id >> 3;
  int mI = q0 & 3, nhi = q0 >> 2;
  int m0 = mI*128, n0 = (nhi*8 + xr_)*128;
  int kbeg = blockIdx.y*kchunk;
  f32x4 acc[4][4];
  #pragma unroll
  for(int i=0;i<4;i++)
    #pragma unroll
    for(int j=0;j<4;j++) acc[i][j] = (f32x4){0,0,0,0};

  int l = t&63, w = t>>6;
  int wm = (w&1)*64, wn = (w>>1)*64;
  int q = l>>4, r16 = l&15;

  int c0 = t, c1 = t+256;
  const u16*   ga0 = Abt + (size_t)(m0 + (c0>>2))*NK + (c0&3)*8;
  const u16*   ga1 = Abt + (size_t)(m0 + (c1>>2))*NK + (c1&3)*8;
  const float* gb0 = Bwf + (size_t)(n0 + (c0>>2))*NK + (c0&3)*8;
  const float* gb1 = Bwf + (size_t)(n0 + (c1>>2))*NK + (c1&3)*8;
  u16 *la00 = As0 + c0*8, *la01 = As0 + c1*8;
  u16 *la10 = As1 + c0*8, *la11 = As1 + c1*8;
  u16 *lb00 = Bs0 + c0*8, *lb01 = Bs0 + c1*8;
  u16 *lb10 = Bs1 + c0*8, *lb11 = Bs1 + c1*8;

  for(int kk=0; kk<kchunk; kk+=64){
    int k0 = kbeg + kk;
    f32x4 v00a = *(const f32x4*)(gb0 + k0);
    f32x4 v00b = *(const f32x4*)(gb0 + k0 + 4);
    f32x4 v01a = *(const f32x4*)(gb1 + k0);
    f32x4 v01b = *(const f32x4*)(gb1 + k0 + 4);
    f32x4 v10a = *(const f32x4*)(gb0 + k0 + 32);
    f32x4 v10b = *(const f32x4*)(gb0 + k0 + 36);
    f32x4 v11a = *(const f32x4*)(gb1 + k0 + 32);
    f32x4 v11b = *(const f32x4*)(gb1 + k0 + 36);
    uint4 w00 = cvt8(v00a, v00b);
    uint4 w01 = cvt8(v01a, v01b);
    uint4 w10 = cvt8(v10a, v10b);
    uint4 w11 = cvt8(v11a, v11b);
    __syncthreads();
    gld16(la00, ga0 + k0);      gld16(la01, ga1 + k0);
    gld16(la10, ga0 + k0 + 32); gld16(la11, ga1 + k0 + 32);
    *(uint4*)lb00 = w00; *(uint4*)lb01 = w01;
    *(uint4*)lb10 = w10; *(uint4*)lb11 = w11;
    __syncthreads();
    {
      bf16x8 af[4], bfr[4];
      #pragma unroll
      for(int mt=0;mt<4;mt++) af[mt]  = *(const bf16x8*)(As0 + (wm+mt*16+r16)*32 + q*8);
      #pragma unroll
      for(int nt=0;nt<4;nt++) bfr[nt] = *(const bf16x8*)(Bs0 + (wn+nt*16+r16)*32 + q*8);
      #pragma unroll
      for(int mt=0;mt<4;mt++)
        #pragma unroll
        for(int nt=0;nt<4;nt++)
          acc[mt][nt] = __builtin_amdgcn_mfma_f32_16x16x32_bf16(af[mt], bfr[nt], acc[mt][nt], 0,0,0);
    }
    {
      bf16x8 af[4], bfr[4];
      #pragma unroll
      for(int mt=0;mt<4;mt++) af[mt]  = *(const bf16x8*)(As1 + (wm+mt*16+r16)*32 + q*8);
      #pragma unroll
      for(int nt=0;nt<4;nt++) bfr[nt] = *(const bf16x8*)(Bs1 + (wn+nt*16+r16)*32 + q*8);
      #pragma unroll
      for(int mt=0;mt<4;mt++)
        #pragma unroll
        for(int nt=0;nt<4;nt++)
          acc[mt][nt] = __builtin_amdgcn_mfma_f32_16x16x32_bf16(af[mt], bfr[nt], acc[mt][nt], 0,0,0);
    }
  }
  u16* op = yp + (size_t)blockIdx.y*NP*NC;
  #pragma unroll
  for(int mt=0;mt<4;mt++)
    #pragma unroll
    for(int nt=0;nt<4;nt++)
      #pragma unroll
      for(int rr=0;rr<4;rr++){
        int m = m0 + wm + mt*16 + q*4 + rr;
        int n = n0 + wn + nt*16 + r16;
        op[(size_t)m*NC + n] = f2b(acc[mt][nt][rr]);
      }
}

// ------ k_post: sum split-K (bf16), conv_b+BN+relu+residual+LayerNorm ----
__global__ __launch_bounds__(256) void k_post(
    const u16* __restrict__ yp, int nparts,
    const float* __restrict__ x,
    const float* __restrict__ cb, const float* __restrict__ bg,
    const float* __restrict__ bb, const float* __restrict__ bm,
    const float* __restrict__ bv, const float* __restrict__ lg,
    const float* __restrict__ lb, float* __restrict__ out){
  int n = threadIdx.x, bs = blockIdx.x;
  float v[16];
  #pragma unroll
  for(int h=0;h<16;h++) v[h]=0.f;
  for(int p=0;p<nparts;p++){
    const u16* pp = yp + (size_t)p*NP*NC + (size_t)bs*NC + n*16;
    uint4 u0 = ((const uint4*)pp)[0];
    uint4 u1 = ((const uint4*)pp)[1];
    float lo, hi;
    un2(u0.x,lo,hi); v[0]+=lo;  v[1]+=hi;
    un2(u0.y,lo,hi); v[2]+=lo;  v[3]+=hi;
    un2(u0.z,lo,hi); v[4]+=lo;  v[5]+=hi;
    un2(u0.w,lo,hi); v[6]+=lo;  v[7]+=hi;
    un2(u1.x,lo,hi); v[8]+=lo;  v[9]+=hi;
    un2(u1.y,lo,hi); v[10]+=lo; v[11]+=hi;
    un2(u1.z,lo,hi); v[12]+=lo; v[13]+=hi;
    un2(u1.w,lo,hi); v[14]+=lo; v[15]+=hi;
  }
  const float* xp = x + ((size_t)bs*NN + n)*NH;
  float xr[16];
  #pragma unroll
  for(int g=0;g<4;g++) *(f32x4*)&xr[g*4] = ((const f32x4*)xp)[g];

  float mu = 0.f;
  #pragma unroll
  for(int h=0;h<16;h++){
    int co = n*16 + h;
    float t1 = v[h] + cb[co];
    t1 = (t1 - bm[co]) * (1.f/sqrtf(bv[co] + EPSV));
    t1 = t1 * bg[co] + bb[co];
    t1 = fmaxf(t1, 0.f);
    t1 += xr[h];
    v[h] = t1; mu += t1;
  }
  mu *= (1.f/16.f);
  float var = 0.f;
  #pragma unroll
  for(int h=0;h<16;h++){ float d = v[h]-mu; var = fmaf(d,d,var); }
  var *= (1.f/16.f);
  float rs = 1.f/sqrtf(var + EPSV);
  float* op = out + ((size_t)bs*NN + n)*NH;
  #pragma unroll
  for(int h=0;h<16;h++) op[h] = (v[h]-mu)*rs*lg[h] + lb[h];
}

extern "C" void kernel_launch(void* const* d_in, const int* in_sizes, int n_in,
                              void* d_out, int out_size, void* d_ws, size_t ws_size,
                              hipStream_t stream){
  const float* x   = (const float*)d_in[0];
  const float* adj = (const float*)d_in[1];
  const float* W   = (const float*)d_in[2];
  const float* a1  = (const float*)d_in[3];
  const float* a2  = (const float*)d_in[4];
  const float* cw  = (const float*)d_in[5];
  const float* cb  = (const float*)d_in[6];
  const float* bg  = (const float*)d_in[7];
  const float* bb  = (const float*)d_in[8];
  const float* bm  = (const float*)d_in[9];
  const float* bv  = (const float*)d_in[10];
  const float* lg  = (const float*)d_in[11];
  const float* lb  = (const float*)d_in[12];
  float* out = (float*)d_out;

  char* ws = (char*)d_ws;
  const size_t ypb = (size_t)NP*NC*2;                 // 4 MB per split part

  // ---- new path layout: am | Sp | Bt | yp  (~49 MB for P=8) ----
  const size_t SP_OFF  = 8192;                        // after am (8 KB)
  const size_t SP_SZ   = (size_t)NB*SROW*NC*2;        // 4.33 MB padded spatial
  const size_t BT_OFF2 = SP_OFF + SP_SZ;
  const size_t BT_SZ   = (size_t)NP*NK*2;             // 12.6 MB im2col
  const size_t YP_OFF2 = BT_OFF2 + BT_SZ;

  u64* am = (u64*)ws;

  int P2 = 0;
  if(ws_size >= YP_OFF2 + 8*ypb)      P2 = 8;
  else if(ws_size >= YP_OFF2 + 4*ypb) P2 = 4;
  else if(ws_size >= YP_OFF2 + 2*ypb) P2 = 2;
  else if(ws_size >= YP_OFF2 + 1*ypb) P2 = 1;

  if(P2){
    u16* Sp = (u16*)(ws + SP_OFF);
    u16* Bt = (u16*)(ws + BT_OFF2);
    u16* yp = (u16*)(ws + YP_OFF2);
    hipLaunchKernelGGL(k_adj,  dim3(64),      dim3(256), 0, stream, adj, am, (uint4*)Sp);
    hipLaunchKernelGGL(k_attn, dim3(NP),      dim3(256), 0, stream, x,W,a1,a2,am,Sp);
    hipLaunchKernelGGL(k_i2c,  dim3(NP),      dim3(256), 0, stream, Sp, Bt);
    hipLaunchKernelGGL(k_gemm, dim3(32,P2),   dim3(512), 0, stream, Bt, cw, yp, NK/P2);
    hipLaunchKernelGGL(k_post, dim3(NP),      dim3(256), 0, stream, yp,P2,x,cb,bg,bb,bm,bv,lg,lb,out);
  } else {
    // fallback: previous verified path (scatter im2col + fused-cvt GEMM)
    const size_t BT_OFF = 8192;
    const size_t YP_OFF = BT_OFF + (size_t)NP*NK*2;
    int P = 1;
    if(ws_size >= YP_OFF + 8*ypb)      P = 8;
    else if(ws_size >= YP_OFF + 4*ypb) P = 4;
    else if(ws_size >= YP_OFF + 2*ypb) P = 2;
    u16* Bt = (u16*)(ws + BT_OFF);
    u16* yp = (u16*)(ws + YP_OFF);
    hipLaunchKernelGGL(k_adj,    dim3(64),     dim3(256), 0, stream, adj, am, (uint4*)0);
    hipLaunchKernelGGL(k_attn_s, dim3(NP),     dim3(256), 0, stream, x,W,a1,a2,am,Bt);
    hipLaunchKernelGGL(k_gemm_f, dim3(128,P),  dim3(256), 0, stream, Bt, cw, yp, NK/P);
    hipLaunchKernelGGL(k_post,   dim3(NP),     dim3(256), 0, stream, yp,P,x,cb,bg,bb,bm,bv,lg,lb,out);
  }
}